// Round 1
// baseline (90.207 us; speedup 1.0000x reference)
//
#include <hip/hip_runtime.h>
#include <math.h>

#define BDIM 256
#define DD 16
#define NTOK 256
#define STRIDE 20   // floats per LDS row: 80B, 16B-aligned, bank-conflict-free

__device__ __forceinline__ float safe_acos(float u) {
    return (fabsf(u) <= 1.0f) ? acosf(u) : 0.0f;
}

__global__ __launch_bounds__(BDIM, 1) void qab_kernel(
    const float* __restrict__ x,
    const float* __restrict__ ln1_g, const float* __restrict__ ln1_b,
    const float* __restrict__ angles,
    const float* __restrict__ ln2_g, const float* __restrict__ ln2_b,
    const float* __restrict__ w1, const float* __restrict__ b1,
    const float* __restrict__ w2, const float* __restrict__ b2,
    float* __restrict__ out)
{
    __shared__ float a_lds[NTOK][STRIDE];   // signed amplitudes
    __shared__ float vx_lds[NTOK][STRIDE];  // |W a|
    __shared__ float W_lds[DD][DD];
    __shared__ float w1_lds[DD * 64];
    __shared__ float w2_lds[64 * DD];

    const int b = blockIdx.x;
    const int row = threadIdx.x;

    // ---- stage MLP weights ----
    for (int i = row; i < DD * 64; i += BDIM) {
        w1_lds[i] = w1[i];
        w2_lds[i] = w2[i];
    }

    // ---- butterfly matrix: lane c owns column c of M (16x16) ----
    if (row < DD) {
        float m[DD];
        #pragma unroll
        for (int r = 0; r < DD; ++r) m[r] = (r == row) ? 1.0f : 0.0f;
        #pragma unroll
        for (int s = 0; s < 4; ++s) {
            const int step = 1 << s;
            #pragma unroll
            for (int p = 0; p < 8; ++p) {
                const int i = ((p >> s) << (s + 1)) | (p & (step - 1));
                const int j = i + step;
                float ang = angles[s * 8 + p];
                float sn, c;
                sincosf(ang, &sn, &c);
                float mi = m[i], mj = m[j];
                m[i] =  c * mi + sn * mj;
                m[j] = -sn * mi + c * mj;
            }
        }
        #pragma unroll
        for (int r = 0; r < DD; ++r) W_lds[r][row] = m[r];
    }

    // ---- load my row of x ----
    const float* xrow = x + ((size_t)b * NTOK + row) * DD;
    float xr[DD];
    #pragma unroll
    for (int q = 0; q < 4; ++q) {
        float4 v = ((const float4*)xrow)[q];
        xr[4*q+0] = v.x; xr[4*q+1] = v.y; xr[4*q+2] = v.z; xr[4*q+3] = v.w;
    }

    // ---- LN1, /2 ----
    float mu = 0.0f;
    #pragma unroll
    for (int d = 0; d < DD; ++d) mu += xr[d];
    mu *= (1.0f / DD);
    float var = 0.0f;
    #pragma unroll
    for (int d = 0; d < DD; ++d) { float dv = xr[d] - mu; var += dv * dv; }
    var *= (1.0f / DD);
    float rs = 1.0f / sqrtf(var + 1e-5f);
    float inp[DD];
    #pragma unroll
    for (int d = 0; d < DD; ++d)
        inp[d] = ((xr[d] - mu) * rs * ln1_g[d] + ln1_b[d]) * 0.5f;

    // ---- RBS angles + amplitudes (fused; replicates fp32 op order) ----
    float amp[DD];
    {
        float a_prev = safe_acos(inp[0]);
        float t = 1.0f, prefix = 1.0f;
        #pragma unroll
        for (int i = 1; i < DD - 1; ++i) {
            float si, ci;
            sincosf(a_prev, &si, &ci);
            amp[i - 1] = prefix * ci;
            prefix *= si;
            float inv = 1.0f / si;
            if (isinf(inv)) inv = copysignf(3.4028234663852886e38f, inv); // nan_to_num
            t = t * inv;
            a_prev = safe_acos(inp[i] * t);
        }
        float si, ci;
        sincosf(a_prev, &si, &ci);
        amp[DD - 2] = prefix * ci;
        prefix *= si;
        amp[DD - 1] = prefix;
    }

    // ---- stash a (signed) in LDS ----
    #pragma unroll
    for (int q = 0; q < 4; ++q) {
        float4 v = make_float4(amp[4*q], amp[4*q+1], amp[4*q+2], amp[4*q+3]);
        *(float4*)&a_lds[row][4*q] = v;
    }
    __syncthreads();   // covers W_lds, w1/w2, a_lds

    // ---- Wa = W @ a  (W broadcast from LDS) ----
    float Wa[DD];
    #pragma unroll
    for (int d = 0; d < DD; ++d) {
        float s = 0.0f;
        #pragma unroll
        for (int e = 0; e < DD; ++e) s += W_lds[d][e] * amp[e];
        Wa[d] = s;
    }
    #pragma unroll
    for (int q = 0; q < 4; ++q) {
        float4 v = make_float4(fabsf(Wa[4*q]), fabsf(Wa[4*q+1]),
                               fabsf(Wa[4*q+2]), fabsf(Wa[4*q+3]));
        *(float4*)&vx_lds[row][4*q] = v;
    }
    __syncthreads();

    // ---- online softmax over j: xwx[i,j] = |Wa_i . a_j| ----
    float mrun = -INFINITY, lrun = 0.0f;
    float acc[DD];
    #pragma unroll
    for (int d = 0; d < DD; ++d) acc[d] = 0.0f;

    for (int j = 0; j < NTOK; ++j) {
        float s = 0.0f;
        #pragma unroll
        for (int q = 0; q < 4; ++q) {
            float4 aj = *(const float4*)&a_lds[j][4*q];
            s += Wa[4*q+0] * aj.x;
            s += Wa[4*q+1] * aj.y;
            s += Wa[4*q+2] * aj.z;
            s += Wa[4*q+3] * aj.w;
        }
        s = fabsf(s);
        float mn = fmaxf(mrun, s);
        float f = __expf(mrun - mn);   // exp(-inf)=0 on first iter
        float p = __expf(s - mn);
        lrun = lrun * f + p;
        #pragma unroll
        for (int q = 0; q < 4; ++q) {
            float4 vj = *(const float4*)&vx_lds[j][4*q];
            acc[4*q+0] = acc[4*q+0] * f + p * vj.x;
            acc[4*q+1] = acc[4*q+1] * f + p * vj.y;
            acc[4*q+2] = acc[4*q+2] * f + p * vj.z;
            acc[4*q+3] = acc[4*q+3] * f + p * vj.w;
        }
        mrun = mn;
    }
    float rl = 1.0f / lrun;
    float o1[DD];
    #pragma unroll
    for (int d = 0; d < DD; ++d) o1[d] = xr[d] + acc[d] * rl;

    // ---- LN2 ----
    float mu2 = 0.0f;
    #pragma unroll
    for (int d = 0; d < DD; ++d) mu2 += o1[d];
    mu2 *= (1.0f / DD);
    float var2 = 0.0f;
    #pragma unroll
    for (int d = 0; d < DD; ++d) { float dv = o1[d] - mu2; var2 += dv * dv; }
    var2 *= (1.0f / DD);
    float rs2 = 1.0f / sqrtf(var2 + 1e-5f);
    float h[DD];
    #pragma unroll
    for (int d = 0; d < DD; ++d)
        h[d] = (o1[d] - mu2) * rs2 * ln2_g[d] + ln2_b[d];

    // ---- MLP: gelu(h@w1+b1)@w2 + b2, streamed over k ----
    float acc2[DD];
    #pragma unroll
    for (int d = 0; d < DD; ++d) acc2[d] = 0.0f;
    for (int k = 0; k < 64; ++k) {
        float tk = b1[k];
        #pragma unroll
        for (int e = 0; e < DD; ++e) tk += h[e] * w1_lds[e * 64 + k];
        float g = 0.5f * tk * (1.0f + erff(tk * 0.70710678118654752f)); // exact gelu
        #pragma unroll
        for (int d = 0; d < DD; ++d) acc2[d] += g * w2_lds[k * DD + d];
    }

    // ---- out = o1 + mlp ----
    float* orow = out + ((size_t)b * NTOK + row) * DD;
    #pragma unroll
    for (int q = 0; q < 4; ++q) {
        float4 v;
        v.x = o1[4*q+0] + acc2[4*q+0] + b2[4*q+0];
        v.y = o1[4*q+1] + acc2[4*q+1] + b2[4*q+1];
        v.z = o1[4*q+2] + acc2[4*q+2] + b2[4*q+2];
        v.w = o1[4*q+3] + acc2[4*q+3] + b2[4*q+3];
        ((float4*)orow)[q] = v;
    }
}

extern "C" void kernel_launch(void* const* d_in, const int* in_sizes, int n_in,
                              void* d_out, int out_size, void* d_ws, size_t ws_size,
                              hipStream_t stream) {
    const float* x     = (const float*)d_in[0];
    const float* ln1_g = (const float*)d_in[1];
    const float* ln1_b = (const float*)d_in[2];
    const float* ang   = (const float*)d_in[3];
    const float* ln2_g = (const float*)d_in[4];
    const float* ln2_b = (const float*)d_in[5];
    const float* w1    = (const float*)d_in[6];
    const float* b1    = (const float*)d_in[7];
    const float* w2    = (const float*)d_in[8];
    const float* b2    = (const float*)d_in[9];
    float* out = (float*)d_out;

    const int B = in_sizes[0] / (NTOK * DD);
    hipLaunchKernelGGL(qab_kernel, dim3(B), dim3(BDIM), 0, stream,
                       x, ln1_g, ln1_b, ang, ln2_g, ln2_b, w1, b1, w2, b2, out);
}

// Round 2
// 65.316 us; speedup vs baseline: 1.3811x; 1.3811x over previous
//
#include <hip/hip_runtime.h>
#include <math.h>

#define BDIM 512
#define DD 16
#define NTOK 256
#define STRIDE 20   // floats per LDS row: 80B, 16B-aligned

typedef float v2f __attribute__((ext_vector_type(2)));

// float offsets into the shared buffer
#define A_OFF   0                 // a amplitudes      256*20
#define WA_OFF  5120              // Wa signed         256*20  (later reused for h)
#define VX_OFF  10240             // |Wa|              256*20  (later reused for l-partials)
#define W_OFF   15360             // butterfly W       16*16
#define W1T_OFF 15616             // w1 transposed     64*16
#define W2_OFF  16640             // w2 row-major      64*16
#define SM_TOT  17664             // 70656 bytes

__device__ __forceinline__ float safe_acos(float u) {
    return (fabsf(u) <= 1.0f) ? acosf(u) : 0.0f;
}
__device__ __forceinline__ v2f lo2(float4 v){ v2f r; r.x=v.x; r.y=v.y; return r; }
__device__ __forceinline__ v2f hi2(float4 v){ v2f r; r.x=v.z; r.y=v.w; return r; }
#define FMA2 __builtin_elementwise_fma

__global__ __launch_bounds__(BDIM, 4) void qab_kernel(
    const float* __restrict__ x,
    const float* __restrict__ ln1_g, const float* __restrict__ ln1_b,
    const float* __restrict__ angles,
    const float* __restrict__ ln2_g, const float* __restrict__ ln2_b,
    const float* __restrict__ w1, const float* __restrict__ b1,
    const float* __restrict__ w2, const float* __restrict__ b2,
    float* __restrict__ out)
{
    __shared__ float sm[SM_TOT];

    const int b   = blockIdx.x;
    const int tid = threadIdx.x;
    const int r   = tid & (NTOK - 1);   // token row
    const int q   = tid >> 8;           // 0/1: which half of j / k space

    // ---------------- phase 0: stage weights / W / per-row prep ----------------
    if (q == 1) {
        // w1 transposed (w1t[k*16+e] = w1[e*64+k]) and w2 row-major
        for (int i = r; i < 64 * DD; i += NTOK) {
            int k = i >> 4, e = i & 15;
            sm[W1T_OFF + i] = w1[e * 64 + k];
            sm[W2_OFF  + i] = w2[i];
        }
    }
    if (tid < DD) {
        // butterfly matrix: lane c owns column c
        float m[DD];
        #pragma unroll
        for (int rr = 0; rr < DD; ++rr) m[rr] = (rr == tid) ? 1.0f : 0.0f;
        #pragma unroll
        for (int s = 0; s < 4; ++s) {
            const int step = 1 << s;
            #pragma unroll
            for (int p = 0; p < 8; ++p) {
                const int i = ((p >> s) << (s + 1)) | (p & (step - 1));
                const int j = i + step;
                float sn, c;
                sincosf(angles[s * 8 + p], &sn, &c);
                float mi = m[i], mj = m[j];
                m[i] =  c * mi + sn * mj;
                m[j] = -sn * mi + c * mj;
            }
        }
        #pragma unroll
        for (int rr = 0; rr < DD; ++rr) sm[W_OFF + rr * DD + tid] = m[rr];
    }

    float xr[DD];
    float amp[DD];
    if (q == 0) {
        const float* xrow = x + ((size_t)b * NTOK + r) * DD;
        #pragma unroll
        for (int qq = 0; qq < 4; ++qq) {
            float4 v = ((const float4*)xrow)[qq];
            xr[4*qq+0] = v.x; xr[4*qq+1] = v.y; xr[4*qq+2] = v.z; xr[4*qq+3] = v.w;
        }
        // LN1, /2
        float mu = 0.0f;
        #pragma unroll
        for (int d = 0; d < DD; ++d) mu += xr[d];
        mu *= (1.0f / DD);
        float var = 0.0f;
        #pragma unroll
        for (int d = 0; d < DD; ++d) { float dv = xr[d] - mu; var += dv * dv; }
        var *= (1.0f / DD);
        float rs = 1.0f / sqrtf(var + 1e-5f);
        float inp[DD];
        #pragma unroll
        for (int d = 0; d < DD; ++d)
            inp[d] = ((xr[d] - mu) * rs * ln1_g[d] + ln1_b[d]) * 0.5f;

        // RBS spherical decomposition -> amplitudes (fp32 op order as reference)
        {
            float a_prev = safe_acos(inp[0]);
            float t = 1.0f, prefix = 1.0f;
            #pragma unroll
            for (int i = 1; i < DD - 1; ++i) {
                float si, ci;
                sincosf(a_prev, &si, &ci);
                amp[i - 1] = prefix * ci;
                prefix *= si;
                float inv = 1.0f / si;
                if (isinf(inv)) inv = copysignf(3.4028234663852886e38f, inv);
                t = t * inv;
                a_prev = safe_acos(inp[i] * t);
            }
            float si, ci;
            sincosf(a_prev, &si, &ci);
            amp[DD - 2] = prefix * ci;
            prefix *= si;
            amp[DD - 1] = prefix;
        }
        #pragma unroll
        for (int qq = 0; qq < 4; ++qq)
            *(float4*)&sm[A_OFF + r * STRIDE + 4*qq] =
                make_float4(amp[4*qq], amp[4*qq+1], amp[4*qq+2], amp[4*qq+3]);
    }
    __syncthreads();

    // ---------------- phase 1: Wa = W @ a (q0 only) ----------------
    if (q == 0) {
        float Wa[DD];
        #pragma unroll
        for (int d = 0; d < DD; ++d) {
            float s = 0.0f;
            #pragma unroll
            for (int e = 0; e < DD; ++e) s += sm[W_OFF + d * DD + e] * amp[e];
            Wa[d] = s;
        }
        #pragma unroll
        for (int qq = 0; qq < 4; ++qq) {
            *(float4*)&sm[WA_OFF + r * STRIDE + 4*qq] =
                make_float4(Wa[4*qq], Wa[4*qq+1], Wa[4*qq+2], Wa[4*qq+3]);
            *(float4*)&sm[VX_OFF + r * STRIDE + 4*qq] =
                make_float4(fabsf(Wa[4*qq]), fabsf(Wa[4*qq+1]),
                            fabsf(Wa[4*qq+2]), fabsf(Wa[4*qq+3]));
        }
    }
    __syncthreads();

    // ---------------- phase 2: flash softmax over my half of j ----------------
    v2f wa2[8];
    #pragma unroll
    for (int qq = 0; qq < 4; ++qq) {
        float4 v = *(const float4*)&sm[WA_OFF + r * STRIDE + 4*qq];
        wa2[2*qq]   = lo2(v);
        wa2[2*qq+1] = hi2(v);
    }

    v2f acc[8];
    #pragma unroll
    for (int k = 0; k < 8; ++k) { acc[k].x = 0.0f; acc[k].y = 0.0f; }
    float l = 0.0f;
    const int j0 = q * (NTOK / 2);

    #pragma unroll 4
    for (int jj = 0; jj < NTOK / 2; ++jj) {
        const int j = j0 + jj;
        const float* aj = &sm[A_OFF + j * STRIDE];
        float4 a0 = *(const float4*)(aj);
        float4 a1 = *(const float4*)(aj + 4);
        float4 a2 = *(const float4*)(aj + 8);
        float4 a3 = *(const float4*)(aj + 12);
        v2f s2 = FMA2(wa2[0], lo2(a0), (v2f)(0.0f));
        s2 = FMA2(wa2[1], hi2(a0), s2);
        s2 = FMA2(wa2[2], lo2(a1), s2);
        s2 = FMA2(wa2[3], hi2(a1), s2);
        s2 = FMA2(wa2[4], lo2(a2), s2);
        s2 = FMA2(wa2[5], hi2(a2), s2);
        s2 = FMA2(wa2[6], lo2(a3), s2);
        s2 = FMA2(wa2[7], hi2(a3), s2);
        float s = fabsf(s2.x + s2.y);
        float p = __expf(s);      // s in [0,1] -> no max subtraction needed
        l += p;
        v2f pp; pp.x = p; pp.y = p;
        const float* vj = &sm[VX_OFF + j * STRIDE];
        float4 v0 = *(const float4*)(vj);
        float4 v1 = *(const float4*)(vj + 4);
        float4 v2 = *(const float4*)(vj + 8);
        float4 v3 = *(const float4*)(vj + 12);
        acc[0] = FMA2(pp, lo2(v0), acc[0]);
        acc[1] = FMA2(pp, hi2(v0), acc[1]);
        acc[2] = FMA2(pp, lo2(v1), acc[2]);
        acc[3] = FMA2(pp, hi2(v1), acc[3]);
        acc[4] = FMA2(pp, lo2(v2), acc[4]);
        acc[5] = FMA2(pp, hi2(v2), acc[5]);
        acc[6] = FMA2(pp, lo2(v3), acc[6]);
        acc[7] = FMA2(pp, hi2(v3), acc[7]);
    }
    __syncthreads();   // all loop reads of a/vx done

    // q1 publishes partials (reuse a region for acc, vx region for l)
    if (q == 1) {
        #pragma unroll
        for (int qq = 0; qq < 4; ++qq) {
            float4 v;
            v.x = acc[2*qq].x;   v.y = acc[2*qq].y;
            v.z = acc[2*qq+1].x; v.w = acc[2*qq+1].y;
            *(float4*)&sm[A_OFF + r * STRIDE + 4*qq] = v;
        }
        sm[VX_OFF + r] = l;
    }
    __syncthreads();

    // ---------------- phase 3: combine + o1 + LN2 (q0) ----------------
    float o1[DD];
    float h[DD];
    if (q == 0) {
        l += sm[VX_OFF + r];
        float rl = 1.0f / l;
        #pragma unroll
        for (int qq = 0; qq < 4; ++qq) {
            float4 v = *(const float4*)&sm[A_OFF + r * STRIDE + 4*qq];
            o1[4*qq+0] = xr[4*qq+0] + (acc[2*qq].x   + v.x) * rl;
            o1[4*qq+1] = xr[4*qq+1] + (acc[2*qq].y   + v.y) * rl;
            o1[4*qq+2] = xr[4*qq+2] + (acc[2*qq+1].x + v.z) * rl;
            o1[4*qq+3] = xr[4*qq+3] + (acc[2*qq+1].y + v.w) * rl;
        }
        float mu2 = 0.0f;
        #pragma unroll
        for (int d = 0; d < DD; ++d) mu2 += o1[d];
        mu2 *= (1.0f / DD);
        float var2 = 0.0f;
        #pragma unroll
        for (int d = 0; d < DD; ++d) { float dv = o1[d] - mu2; var2 += dv * dv; }
        var2 *= (1.0f / DD);
        float rs2 = 1.0f / sqrtf(var2 + 1e-5f);
        #pragma unroll
        for (int d = 0; d < DD; ++d)
            h[d] = (o1[d] - mu2) * rs2 * ln2_g[d] + ln2_b[d];
        // publish h (reuse Wa region)
        #pragma unroll
        for (int qq = 0; qq < 4; ++qq)
            *(float4*)&sm[WA_OFF + r * STRIDE + 4*qq] =
                make_float4(h[4*qq], h[4*qq+1], h[4*qq+2], h[4*qq+3]);
    }
    __syncthreads();

    // ---------------- phase 4: MLP, split over k ----------------
    v2f h2[8];
    #pragma unroll
    for (int qq = 0; qq < 4; ++qq) {
        float4 v = *(const float4*)&sm[WA_OFF + r * STRIDE + 4*qq];
        h2[2*qq]   = lo2(v);
        h2[2*qq+1] = hi2(v);
    }
    v2f acc2[8];
    #pragma unroll
    for (int k = 0; k < 8; ++k) { acc2[k].x = 0.0f; acc2[k].y = 0.0f; }
    const int k0 = q * 32;
    for (int kk = 0; kk < 32; ++kk) {
        const int k = k0 + kk;
        const float* w1r = &sm[W1T_OFF + k * DD];
        float4 b0 = *(const float4*)(w1r);
        float4 b1v = *(const float4*)(w1r + 4);
        float4 b2v = *(const float4*)(w1r + 8);
        float4 b3 = *(const float4*)(w1r + 12);
        v2f t2 = FMA2(h2[0], lo2(b0), (v2f)(0.0f));
        t2 = FMA2(h2[1], hi2(b0), t2);
        t2 = FMA2(h2[2], lo2(b1v), t2);
        t2 = FMA2(h2[3], hi2(b1v), t2);
        t2 = FMA2(h2[4], lo2(b2v), t2);
        t2 = FMA2(h2[5], hi2(b2v), t2);
        t2 = FMA2(h2[6], lo2(b3), t2);
        t2 = FMA2(h2[7], hi2(b3), t2);
        float tk = b1[k] + t2.x + t2.y;
        float g = 0.5f * tk * (1.0f + erff(tk * 0.70710678118654752f));
        v2f gg; gg.x = g; gg.y = g;
        const float* w2r = &sm[W2_OFF + k * DD];
        float4 c0 = *(const float4*)(w2r);
        float4 c1 = *(const float4*)(w2r + 4);
        float4 c2 = *(const float4*)(w2r + 8);
        float4 c3 = *(const float4*)(w2r + 12);
        acc2[0] = FMA2(gg, lo2(c0), acc2[0]);
        acc2[1] = FMA2(gg, hi2(c0), acc2[1]);
        acc2[2] = FMA2(gg, lo2(c1), acc2[2]);
        acc2[3] = FMA2(gg, hi2(c1), acc2[3]);
        acc2[4] = FMA2(gg, lo2(c2), acc2[4]);
        acc2[5] = FMA2(gg, hi2(c2), acc2[5]);
        acc2[6] = FMA2(gg, lo2(c3), acc2[6]);
        acc2[7] = FMA2(gg, hi2(c3), acc2[7]);
    }
    __syncthreads();   // a region reads (combine) done earlier; safe to reuse

    if (q == 1) {
        #pragma unroll
        for (int qq = 0; qq < 4; ++qq) {
            float4 v;
            v.x = acc2[2*qq].x;   v.y = acc2[2*qq].y;
            v.z = acc2[2*qq+1].x; v.w = acc2[2*qq+1].y;
            *(float4*)&sm[A_OFF + r * STRIDE + 4*qq] = v;
        }
    }
    __syncthreads();

    // ---------------- phase 5: out = o1 + mlp + b2 (q0) ----------------
    if (q == 0) {
        float* orow = out + ((size_t)b * NTOK + r) * DD;
        #pragma unroll
        for (int qq = 0; qq < 4; ++qq) {
            float4 v = *(const float4*)&sm[A_OFF + r * STRIDE + 4*qq];
            float4 o;
            o.x = o1[4*qq+0] + acc2[2*qq].x   + v.x + b2[4*qq+0];
            o.y = o1[4*qq+1] + acc2[2*qq].y   + v.y + b2[4*qq+1];
            o.z = o1[4*qq+2] + acc2[2*qq+1].x + v.z + b2[4*qq+2];
            o.w = o1[4*qq+3] + acc2[2*qq+1].y + v.w + b2[4*qq+3];
            ((float4*)orow)[qq] = o;
        }
    }
}

extern "C" void kernel_launch(void* const* d_in, const int* in_sizes, int n_in,
                              void* d_out, int out_size, void* d_ws, size_t ws_size,
                              hipStream_t stream) {
    const float* x     = (const float*)d_in[0];
    const float* ln1_g = (const float*)d_in[1];
    const float* ln1_b = (const float*)d_in[2];
    const float* ang   = (const float*)d_in[3];
    const float* ln2_g = (const float*)d_in[4];
    const float* ln2_b = (const float*)d_in[5];
    const float* w1    = (const float*)d_in[6];
    const float* b1    = (const float*)d_in[7];
    const float* w2    = (const float*)d_in[8];
    const float* b2    = (const float*)d_in[9];
    float* out = (float*)d_out;

    const int B = in_sizes[0] / (NTOK * DD);
    hipLaunchKernelGGL(qab_kernel, dim3(B), dim3(BDIM), 0, stream,
                       x, ln1_g, ln1_b, ang, ln2_g, ln2_b, w1, b1, w2, b2, out);
}

// Round 3
// 40.868 us; speedup vs baseline: 2.2073x; 1.5982x over previous
//
#include <hip/hip_runtime.h>
#include <math.h>

#define NTOK 256
#define DD 16
#define BDIM 512

typedef short short8 __attribute__((ext_vector_type(8)));
typedef float f32x16 __attribute__((ext_vector_type(16)));

__device__ __forceinline__ float safe_acos(float u) {
    return (fabsf(u) <= 1.0f) ? acosf(u) : 0.0f;
}
// round-to-nearest-even f32 -> bf16 (no NaN handling needed here)
__device__ __forceinline__ unsigned short f2bf(float f) {
    unsigned int u = __float_as_uint(f);
    u += 0x7FFFu + ((u >> 16) & 1u);
    return (unsigned short)(u >> 16);
}
__device__ __forceinline__ float bf2f(unsigned short h) {
    return __uint_as_float(((unsigned int)h) << 16);
}

__global__ __launch_bounds__(BDIM, 2) void qab_kernel(
    const float* __restrict__ x,
    const float* __restrict__ ln1_g, const float* __restrict__ ln1_b,
    const float* __restrict__ angles,
    const float* __restrict__ ln2_g, const float* __restrict__ ln2_b,
    const float* __restrict__ w1, const float* __restrict__ b1,
    const float* __restrict__ w2, const float* __restrict__ b2,
    float* __restrict__ out)
{
    __shared__ unsigned short a_bf[NTOK][DD];      // amplitudes, bf16          8KB
    __shared__ unsigned short wa_bf[NTOK][DD];     // Wa, bf16                  8KB
    __shared__ unsigned short vxT[17][264];        // |Wa|^T + ones row         ~8.8KB
    __shared__ unsigned short Ptmp[8][32][40];     // per-wave P transpose      20KB
    __shared__ float Olds[NTOK][20];               // O accum / h               20KB
    __shared__ float W_lds[DD][DD];                // butterfly                 1KB
    __shared__ float w1t[64 * DD];                 // w1 transposed             4KB
    __shared__ float w2s[64 * DD];                 // w2 row-major              4KB

    const int b   = blockIdx.x;
    const int tid = threadIdx.x;
    const int r   = tid & (NTOK - 1);
    const int q   = tid >> 8;

    // ---------------- P0: weights, butterfly, per-row prep ----------------
    if (q == 1) {
        for (int i = r; i < 64 * DD; i += NTOK) {
            int k = i >> 4, e = i & 15;
            w1t[i] = w1[e * 64 + k];
            w2s[i] = w2[i];
        }
        vxT[16][r] = 0x3F80;   // bf16 1.0 ones-row (for softmax denominator)
    }
    if (tid < DD) {
        float m[DD];
        #pragma unroll
        for (int rr = 0; rr < DD; ++rr) m[rr] = (rr == tid) ? 1.0f : 0.0f;
        #pragma unroll
        for (int s = 0; s < 4; ++s) {
            const int step = 1 << s;
            #pragma unroll
            for (int p = 0; p < 8; ++p) {
                const int i = ((p >> s) << (s + 1)) | (p & (step - 1));
                const int j = i + step;
                float sn, c;
                sincosf(angles[s * 8 + p], &sn, &c);
                float mi = m[i], mj = m[j];
                m[i] =  c * mi + sn * mj;
                m[j] = -sn * mi + c * mj;
            }
        }
        #pragma unroll
        for (int rr = 0; rr < DD; ++rr) W_lds[rr][tid] = m[rr];
    }

    float amp[DD];
    if (q == 0) {
        const float* xrow = x + ((size_t)b * NTOK + r) * DD;
        float xr[DD];
        #pragma unroll
        for (int qq = 0; qq < 4; ++qq) {
            float4 v = ((const float4*)xrow)[qq];
            xr[4*qq+0] = v.x; xr[4*qq+1] = v.y; xr[4*qq+2] = v.z; xr[4*qq+3] = v.w;
        }
        float mu = 0.0f;
        #pragma unroll
        for (int d = 0; d < DD; ++d) mu += xr[d];
        mu *= (1.0f / DD);
        float var = 0.0f;
        #pragma unroll
        for (int d = 0; d < DD; ++d) { float dv = xr[d] - mu; var += dv * dv; }
        var *= (1.0f / DD);
        float rs = 1.0f / sqrtf(var + 1e-5f);
        float inp[DD];
        #pragma unroll
        for (int d = 0; d < DD; ++d)
            inp[d] = ((xr[d] - mu) * rs * ln1_g[d] + ln1_b[d]) * 0.5f;

        // RBS spherical decomposition -> amplitudes (fp32 op order as reference)
        {
            float a_prev = safe_acos(inp[0]);
            float t = 1.0f, prefix = 1.0f;
            #pragma unroll
            for (int i = 1; i < DD - 1; ++i) {
                float si, ci;
                sincosf(a_prev, &si, &ci);
                amp[i - 1] = prefix * ci;
                prefix *= si;
                float inv = 1.0f / si;
                if (isinf(inv)) inv = copysignf(3.4028234663852886e38f, inv);
                t = t * inv;
                a_prev = safe_acos(inp[i] * t);
            }
            float si, ci;
            sincosf(a_prev, &si, &ci);
            amp[DD - 2] = prefix * ci;
            prefix *= si;
            amp[DD - 1] = prefix;
        }
        short8 v0, v1;
        #pragma unroll
        for (int e = 0; e < 8; ++e) {
            v0[e] = (short)f2bf(amp[e]);
            v1[e] = (short)f2bf(amp[8 + e]);
        }
        *(short8*)&a_bf[r][0] = v0;
        *(short8*)&a_bf[r][8] = v1;
    }
    __syncthreads();

    // ---------------- P1: Wa = W @ a, d-halves split across q ----------------
    {
        float av[DD];
        if (q == 0) {
            #pragma unroll
            for (int d = 0; d < DD; ++d) av[d] = amp[d];
        } else {
            short8 t0 = *(const short8*)&a_bf[r][0];
            short8 t1 = *(const short8*)&a_bf[r][8];
            #pragma unroll
            for (int e = 0; e < 8; ++e) {
                av[e]     = bf2f((unsigned short)t0[e]);
                av[8 + e] = bf2f((unsigned short)t1[e]);
            }
        }
        const int d0 = q * 8;
        #pragma unroll
        for (int dd2 = 0; dd2 < 8; ++dd2) {
            const int d = d0 + dd2;
            float s = 0.0f;
            #pragma unroll
            for (int e = 0; e < DD; ++e) s += W_lds[d][e] * av[e];
            wa_bf[r][d] = f2bf(s);
            vxT[d][r]   = f2bf(fabsf(s));
        }
    }
    __syncthreads();

    // ---------------- P2: MFMA attention. wave w owns i-strip [32w, 32w+32) --
    const int w   = tid >> 6;
    const int l31 = tid & 31;
    const int hi  = (tid >> 5) & 1;

    f32x16 Oacc;
    #pragma unroll
    for (int t = 0; t < 16; ++t) Oacc[t] = 0.0f;
    const f32x16 zc = Oacc;

    // A-frag: Wa[i = 32w + lane%32][k = 8*hi + e]
    short8 waf = *(const short8*)&wa_bf[w * 32 + l31][8 * hi];
    const int ncl = (l31 < 16) ? l31 : 16;   // clamp: cols >=17 read ones-row (ignored)

    for (int jt = 0; jt < 8; ++jt) {
        // B-frag: a[j = 32jt + lane%32][k = 8*hi + e]
        short8 af = *(const short8*)&a_bf[jt * 32 + l31][8 * hi];
        // S[i][j] tile: D col j = lane&31, row i = (t&3)+8*(t>>2)+4*hi
        f32x16 S = __builtin_amdgcn_mfma_f32_32x32x16_bf16(waf, af, zc, 0, 0, 0);
        #pragma unroll
        for (int t = 0; t < 16; ++t) {
            float p = __expf(fabsf(S[t]));   // s in [0,1]: no max subtraction needed
            Ptmp[w][(t & 3) + 8 * (t >> 2) + 4 * hi][l31] = f2bf(p);
        }
        // A-frags of P: row i = lane%32, k = j_local = 16h + 8*hi + e
        short8 pa0 = *(const short8*)&Ptmp[w][l31][8 * hi];
        short8 pa1 = *(const short8*)&Ptmp[w][l31][16 + 8 * hi];
        // B-frags of vx_ext^T: col n = lane%32 (dd / ones), k = same j_local
        short8 vb0 = *(const short8*)&vxT[ncl][jt * 32 + 8 * hi];
        short8 vb1 = *(const short8*)&vxT[ncl][jt * 32 + 16 + 8 * hi];
        Oacc = __builtin_amdgcn_mfma_f32_32x32x16_bf16(pa0, vb0, Oacc, 0, 0, 0);
        Oacc = __builtin_amdgcn_mfma_f32_32x32x16_bf16(pa1, vb1, Oacc, 0, 0, 0);
    }
    #pragma unroll
    for (int t = 0; t < 16; ++t) {
        const int i = w * 32 + (t & 3) + 8 * (t >> 2) + 4 * hi;
        if (l31 < 20) Olds[i][l31] = Oacc[t];   // cols 0..15 = O, 16 = l, 17-19 pad
    }
    __syncthreads();

    // ---------------- P3: o1 = x + O/l, LN2 -> h (q0) ----------------
    float o1[DD];
    if (q == 0) {
        const float rl = 1.0f / Olds[r][16];
        const float* xrow = x + ((size_t)b * NTOK + r) * DD;
        #pragma unroll
        for (int qq = 0; qq < 4; ++qq) {
            float4 v = ((const float4*)xrow)[qq];
            o1[4*qq+0] = v.x + Olds[r][4*qq+0] * rl;
            o1[4*qq+1] = v.y + Olds[r][4*qq+1] * rl;
            o1[4*qq+2] = v.z + Olds[r][4*qq+2] * rl;
            o1[4*qq+3] = v.w + Olds[r][4*qq+3] * rl;
        }
        float mu2 = 0.0f;
        #pragma unroll
        for (int d = 0; d < DD; ++d) mu2 += o1[d];
        mu2 *= (1.0f / DD);
        float var2 = 0.0f;
        #pragma unroll
        for (int d = 0; d < DD; ++d) { float dv = o1[d] - mu2; var2 += dv * dv; }
        var2 *= (1.0f / DD);
        float rs2 = 1.0f / sqrtf(var2 + 1e-5f);
        #pragma unroll
        for (int d = 0; d < DD; ++d)
            Olds[r][d] = (o1[d] - mu2) * rs2 * ln2_g[d] + ln2_b[d];   // h
    }
    __syncthreads();

    // ---------------- P4: MLP, k-halves split across q ----------------
    float h[DD];
    #pragma unroll
    for (int d = 0; d < DD; ++d) h[d] = Olds[r][d];
    float acc2[DD];
    #pragma unroll
    for (int d = 0; d < DD; ++d) acc2[d] = 0.0f;
    const int k0 = q * 32;
    for (int kk = 0; kk < 32; ++kk) {
        const int k = k0 + kk;
        float t = b1[k];
        #pragma unroll
        for (int e = 0; e < DD; ++e) t += h[e] * w1t[k * DD + e];
        float g = 0.5f * t * (1.0f + erff(t * 0.70710678118654752f));
        #pragma unroll
        for (int d = 0; d < DD; ++d) acc2[d] += g * w2s[k * DD + d];
    }
    if (q == 1) {
        float* pex = (float*)Ptmp;   // Ptmp is free after P2
        #pragma unroll
        for (int d = 0; d < DD; ++d) pex[r * 20 + d] = acc2[d];
    }
    __syncthreads();

    // ---------------- P5: out = o1 + mlp + b2 (q0) ----------------
    if (q == 0) {
        const float* pex = (const float*)Ptmp;
        float* orow = out + ((size_t)b * NTOK + r) * DD;
        #pragma unroll
        for (int qq = 0; qq < 4; ++qq) {
            float4 o;
            o.x = o1[4*qq+0] + acc2[4*qq+0] + pex[r * 20 + 4*qq+0] + b2[4*qq+0];
            o.y = o1[4*qq+1] + acc2[4*qq+1] + pex[r * 20 + 4*qq+1] + b2[4*qq+1];
            o.z = o1[4*qq+2] + acc2[4*qq+2] + pex[r * 20 + 4*qq+2] + b2[4*qq+2];
            o.w = o1[4*qq+3] + acc2[4*qq+3] + pex[r * 20 + 4*qq+3] + b2[4*qq+3];
            ((float4*)orow)[qq] = o;
        }
    }
}

extern "C" void kernel_launch(void* const* d_in, const int* in_sizes, int n_in,
                              void* d_out, int out_size, void* d_ws, size_t ws_size,
                              hipStream_t stream) {
    const float* x     = (const float*)d_in[0];
    const float* ln1_g = (const float*)d_in[1];
    const float* ln1_b = (const float*)d_in[2];
    const float* ang   = (const float*)d_in[3];
    const float* ln2_g = (const float*)d_in[4];
    const float* ln2_b = (const float*)d_in[5];
    const float* w1    = (const float*)d_in[6];
    const float* b1    = (const float*)d_in[7];
    const float* w2    = (const float*)d_in[8];
    const float* b2    = (const float*)d_in[9];
    float* out = (float*)d_out;

    const int B = in_sizes[0] / (NTOK * DD);
    hipLaunchKernelGGL(qab_kernel, dim3(B), dim3(BDIM), 0, stream,
                       x, ln1_g, ln1_b, ang, ln2_g, ln2_b, w1, b1, w2, b2, out);
}

// Round 4
// 30.023 us; speedup vs baseline: 3.0046x; 1.3612x over previous
//
#include <hip/hip_runtime.h>
#include <math.h>

#define NTOK 256
#define DD 16
#define BDIM 512

typedef short short8 __attribute__((ext_vector_type(8)));
typedef float f32x16 __attribute__((ext_vector_type(16)));
typedef unsigned int u32;
typedef unsigned long long u64;

__device__ __forceinline__ float safe_acos(float u) {
    return (fabsf(u) <= 1.0f) ? acosf(u) : 0.0f;
}
__device__ __forceinline__ u32 f2bf(float f) {
    u32 u = __float_as_uint(f);
    u += 0x7FFFu + ((u >> 16) & 1u);
    return u >> 16;
}
__device__ __forceinline__ float bf2f(unsigned short h) {
    return __uint_as_float(((u32)h) << 16);
}
struct U128 { u64 a, b; };
// 16B fragment load from an 8B-aligned LDS address (rows padded to 40B)
__device__ __forceinline__ short8 ld8(const unsigned short* p) {
    U128 t;
    t.a = *(const u64*)(p);
    t.b = *(const u64*)(p + 4);
    return __builtin_bit_cast(short8, t);
}
// pack 16 f32 (reg t -> k-offset pat(t,hi)=(t&3)+8*(t>>2)+4*hi) into two
// A/B-fragment short8s with k = 8*hi+e (+16 for f1), via cvt_pk + permlane32_swap
__device__ __forceinline__ void pack_swap16(f32x16 p, short8& f0, short8& f1) {
    u32 W00, W01, W10, W11, W20, W21, W30, W31;
    asm("v_cvt_pk_bf16_f32 %0, %1, %2" : "=v"(W00) : "v"(p[0]),  "v"(p[1]));
    asm("v_cvt_pk_bf16_f32 %0, %1, %2" : "=v"(W01) : "v"(p[2]),  "v"(p[3]));
    asm("v_cvt_pk_bf16_f32 %0, %1, %2" : "=v"(W10) : "v"(p[4]),  "v"(p[5]));
    asm("v_cvt_pk_bf16_f32 %0, %1, %2" : "=v"(W11) : "v"(p[6]),  "v"(p[7]));
    asm("v_cvt_pk_bf16_f32 %0, %1, %2" : "=v"(W20) : "v"(p[8]),  "v"(p[9]));
    asm("v_cvt_pk_bf16_f32 %0, %1, %2" : "=v"(W21) : "v"(p[10]), "v"(p[11]));
    asm("v_cvt_pk_bf16_f32 %0, %1, %2" : "=v"(W30) : "v"(p[12]), "v"(p[13]));
    asm("v_cvt_pk_bf16_f32 %0, %1, %2" : "=v"(W31) : "v"(p[14]), "v"(p[15]));
    // x' = {x.row0, y.row0}; y' = {x.row1, y.row1}
    asm("v_permlane32_swap_b32 %0, %1" : "+v"(W00), "+v"(W10));
    asm("v_permlane32_swap_b32 %0, %1" : "+v"(W01), "+v"(W11));
    asm("v_permlane32_swap_b32 %0, %1" : "+v"(W20), "+v"(W30));
    asm("v_permlane32_swap_b32 %0, %1" : "+v"(W21), "+v"(W31));
    struct { u32 x, y, z, w; } i0{W00, W01, W10, W11}, i1{W20, W21, W30, W31};
    f0 = __builtin_bit_cast(short8, i0);
    f1 = __builtin_bit_cast(short8, i1);
}

__global__ __launch_bounds__(BDIM, 6) void qab_kernel(
    const float* __restrict__ x,
    const float* __restrict__ ln1_g, const float* __restrict__ ln1_b,
    const float* __restrict__ angles,
    const float* __restrict__ ln2_g, const float* __restrict__ ln2_b,
    const float* __restrict__ w1, const float* __restrict__ b1,
    const float* __restrict__ w2, const float* __restrict__ b2,
    float* __restrict__ out)
{
    __shared__ unsigned short a_bf[NTOK][20];    // amplitudes bf16; later h_bf   10K
    __shared__ unsigned short wa_bf[NTOK][20];   // Wa bf16; later o1[0..9] f32   10K
    __shared__ unsigned short vxT[17][264];      // |Wa|^T + ones; later o1[10..15] 8.8K
    __shared__ float Olds[NTOK][17];             // attn O+l; later mlp out       17.4K
    __shared__ float W_lds[DD][DD];              //                               1K
    __shared__ unsigned short w1tb[64][20];      // w1^T bf16 [k][e]              2.5K
    __shared__ unsigned short w2tb[16][68];      // w2^T bf16 [d][k]              2.2K
    __shared__ float b1_lds[64];

    const int b   = blockIdx.x;
    const int tid = threadIdx.x;
    const int r   = tid & (NTOK - 1);
    const int q   = tid >> 8;
    const int w   = tid >> 6;
    const int l31 = tid & 31;
    const int hi  = (tid >> 5) & 1;

    f32x16 zc;
    #pragma unroll
    for (int t = 0; t < 16; ++t) zc[t] = 0.0f;

    // ---------------- P0: staging + butterfly + amplitude prep ----------------
    if (q == 1) {
        for (int i = r; i < 64 * DD; i += NTOK) {
            int k = i >> 4, e = i & 15;
            w1tb[k][e] = (unsigned short)f2bf(w1[e * 64 + k]);
            w2tb[i & 15][i >> 4] = (unsigned short)f2bf(w2[i]);
        }
        if (r < 64) b1_lds[r] = b1[r];
        vxT[16][r] = 0x3F80;   // ones row -> softmax denominator
    }
    if (tid >= 256 && tid < 256 + DD) {
        const int c = tid - 256;
        float m[DD];
        #pragma unroll
        for (int rr = 0; rr < DD; ++rr) m[rr] = (rr == c) ? 1.0f : 0.0f;
        #pragma unroll
        for (int s = 0; s < 4; ++s) {
            const int step = 1 << s;
            #pragma unroll
            for (int p = 0; p < 8; ++p) {
                const int i = ((p >> s) << (s + 1)) | (p & (step - 1));
                const int j = i + step;
                float sn, cs;
                sincosf(angles[s * 8 + p], &sn, &cs);
                float mi = m[i], mj = m[j];
                m[i] =  cs * mi + sn * mj;
                m[j] = -sn * mi + cs * mj;
            }
        }
        #pragma unroll
        for (int rr = 0; rr < DD; ++rr) W_lds[rr][c] = m[rr];
    }

    float amp[DD];
    if (q == 0) {
        const float* xrow = x + ((size_t)b * NTOK + r) * DD;
        float xr[DD];
        #pragma unroll
        for (int qq = 0; qq < 4; ++qq) {
            float4 v = ((const float4*)xrow)[qq];
            xr[4*qq+0] = v.x; xr[4*qq+1] = v.y; xr[4*qq+2] = v.z; xr[4*qq+3] = v.w;
        }
        float mu = 0.0f;
        #pragma unroll
        for (int d = 0; d < DD; ++d) mu += xr[d];
        mu *= (1.0f / DD);
        float var = 0.0f;
        #pragma unroll
        for (int d = 0; d < DD; ++d) { float dv = xr[d] - mu; var += dv * dv; }
        var *= (1.0f / DD);
        float rs = 1.0f / sqrtf(var + 1e-5f);
        float inp[DD];
        #pragma unroll
        for (int d = 0; d < DD; ++d)
            inp[d] = ((xr[d] - mu) * rs * ln1_g[d] + ln1_b[d]) * 0.5f;

        // RBS spherical decomposition (reference fp32 op order)
        {
            float a_prev = safe_acos(inp[0]);
            float t = 1.0f, prefix = 1.0f;
            #pragma unroll
            for (int i = 1; i < DD - 1; ++i) {
                float si, ci;
                sincosf(a_prev, &si, &ci);
                amp[i - 1] = prefix * ci;
                prefix *= si;
                float inv = 1.0f / si;
                if (isinf(inv)) inv = copysignf(3.4028234663852886e38f, inv);
                t = t * inv;
                a_prev = safe_acos(inp[i] * t);
            }
            float si, ci;
            sincosf(a_prev, &si, &ci);
            amp[DD - 2] = prefix * ci;
            prefix *= si;
            amp[DD - 1] = prefix;
        }
        u32 aw[8];
        #pragma unroll
        for (int k = 0; k < 8; ++k)
            asm("v_cvt_pk_bf16_f32 %0, %1, %2" : "=v"(aw[k]) : "v"(amp[2*k]), "v"(amp[2*k+1]));
        *(u64*)&a_bf[r][0]  = (u64)aw[0] | ((u64)aw[1] << 32);
        *(u64*)&a_bf[r][4]  = (u64)aw[2] | ((u64)aw[3] << 32);
        *(u64*)&a_bf[r][8]  = (u64)aw[4] | ((u64)aw[5] << 32);
        *(u64*)&a_bf[r][12] = (u64)aw[6] | ((u64)aw[7] << 32);
    }
    __syncthreads();

    // ---------------- P1: Wa = W @ a (VALU, d-halves split across q) ----------
    {
        float av[DD];
        if (q == 0) {
            #pragma unroll
            for (int d = 0; d < DD; ++d) av[d] = amp[d];
        } else {
            short8 t0 = ld8(&a_bf[r][0]);
            short8 t1 = ld8(&a_bf[r][8]);
            #pragma unroll
            for (int e = 0; e < 8; ++e) {
                av[e]     = bf2f((unsigned short)t0[e]);
                av[8 + e] = bf2f((unsigned short)t1[e]);
            }
        }
        const int d0 = q * 8;
        float wav[8];
        #pragma unroll
        for (int dd2 = 0; dd2 < 8; ++dd2) {
            const int d = d0 + dd2;
            float s = 0.0f;
            #pragma unroll
            for (int e = 0; e < DD; ++e) s += W_lds[d][e] * av[e];
            wav[dd2] = s;
            vxT[d][r] = (unsigned short)f2bf(fabsf(s));
        }
        u32 ww[4];
        #pragma unroll
        for (int k = 0; k < 4; ++k)
            asm("v_cvt_pk_bf16_f32 %0, %1, %2" : "=v"(ww[k]) : "v"(wav[2*k]), "v"(wav[2*k+1]));
        *(u64*)&wa_bf[r][d0]     = (u64)ww[0] | ((u64)ww[1] << 32);
        *(u64*)&wa_bf[r][d0 + 4] = (u64)ww[2] | ((u64)ww[3] << 32);
    }
    __syncthreads();

    // ---------------- P2: MFMA attention (S^T orientation, in-reg P) ----------
    {
        short8 waf = ld8(&wa_bf[w * 32 + l31][8 * hi]);   // B-frag: Wa^T
        const int ncl = (l31 < 16) ? l31 : 16;
        f32x16 Oacc = zc;
        #pragma unroll
        for (int jt = 0; jt < 8; ++jt) {
            short8 af = ld8(&a_bf[jt * 32 + l31][8 * hi]); // A-frag: a rows = j
            // S^T tile: lane holds S[i = 32w + l31][j = 32jt + pat(t,hi)]
            f32x16 S = __builtin_amdgcn_mfma_f32_32x32x16_bf16(af, waf, zc, 0, 0, 0);
            f32x16 pv;
            #pragma unroll
            for (int t = 0; t < 16; ++t) pv[t] = __expf(fabsf(S[t]));  // s in [0,1]
            short8 pa0, pa1;
            pack_swap16(pv, pa0, pa1);
            const unsigned short* vrow = &vxT[ncl][jt * 32 + 8 * hi];
            short8 vb0 = *(const short8*)(vrow);        // 16B-aligned
            short8 vb1 = *(const short8*)(vrow + 16);
            Oacc = __builtin_amdgcn_mfma_f32_32x32x16_bf16(pa0, vb0, Oacc, 0, 0, 0);
            Oacc = __builtin_amdgcn_mfma_f32_32x32x16_bf16(pa1, vb1, Oacc, 0, 0, 0);
        }
        #pragma unroll
        for (int t = 0; t < 16; ++t) {
            const int i = w * 32 + (t & 3) + 8 * (t >> 2) + 4 * hi;
            if (l31 < 17) Olds[i][l31] = Oacc[t];   // 0..15 = O, 16 = l
        }
    }
    __syncthreads();

    // ---------------- P3: o1 = x + O/l, LN2 -> h_bf (q0) ----------------------
    float* o1a = (float*)wa_bf;   // wa_bf dead: 10 f32 per row
    float* o1b = (float*)vxT;     // vxT dead: 6 f32 per row
    if (q == 0) {
        const float rl = 1.0f / Olds[r][16];
        const float* xrow = x + ((size_t)b * NTOK + r) * DD;
        float o1[DD];
        #pragma unroll
        for (int qq = 0; qq < 4; ++qq) {
            float4 v = ((const float4*)xrow)[qq];
            o1[4*qq+0] = v.x + Olds[r][4*qq+0] * rl;
            o1[4*qq+1] = v.y + Olds[r][4*qq+1] * rl;
            o1[4*qq+2] = v.z + Olds[r][4*qq+2] * rl;
            o1[4*qq+3] = v.w + Olds[r][4*qq+3] * rl;
        }
        float mu2 = 0.0f;
        #pragma unroll
        for (int d = 0; d < DD; ++d) mu2 += o1[d];
        mu2 *= (1.0f / DD);
        float var2 = 0.0f;
        #pragma unroll
        for (int d = 0; d < DD; ++d) { float dv = o1[d] - mu2; var2 += dv * dv; }
        var2 *= (1.0f / DD);
        float rs2 = 1.0f / sqrtf(var2 + 1e-5f);
        float hv[DD];
        #pragma unroll
        for (int d = 0; d < DD; ++d)
            hv[d] = (o1[d] - mu2) * rs2 * ln2_g[d] + ln2_b[d];
        u32 hw[8];
        #pragma unroll
        for (int k = 0; k < 8; ++k)
            asm("v_cvt_pk_bf16_f32 %0, %1, %2" : "=v"(hw[k]) : "v"(hv[2*k]), "v"(hv[2*k+1]));
        // stash o1 in dead LDS, then overwrite a_bf with h
        #pragma unroll
        for (int i = 0; i < 10; ++i) o1a[r * 10 + i] = o1[i];
        #pragma unroll
        for (int i = 0; i < 6; ++i)  o1b[r * 6 + i]  = o1[10 + i];
        *(u64*)&a_bf[r][0]  = (u64)hw[0] | ((u64)hw[1] << 32);
        *(u64*)&a_bf[r][4]  = (u64)hw[2] | ((u64)hw[3] << 32);
        *(u64*)&a_bf[r][8]  = (u64)hw[4] | ((u64)hw[5] << 32);
        *(u64*)&a_bf[r][12] = (u64)hw[6] | ((u64)hw[7] << 32);
    }
    __syncthreads();

    // ---------------- P4: MLP via MFMA (wave w -> token strip 32w) -------------
    {
        short8 hf = ld8(&a_bf[32 * w + l31][8 * hi]);   // B-frag: h^T
        f32x16 O2 = zc;
        #pragma unroll
        for (int kblk = 0; kblk < 2; ++kblk) {
            short8 w1f = ld8(&w1tb[32 * kblk + l31][8 * hi]);   // A-frag: w1^T rows
            // h1^T tile: lane holds h1T[k = 32kblk + pat(t,hi)][tok = 32w + l31]
            f32x16 H = __builtin_amdgcn_mfma_f32_32x32x16_bf16(w1f, hf, zc, 0, 0, 0);
            f32x16 gv;
            #pragma unroll
            for (int t = 0; t < 16; ++t) {
                const int k = 32 * kblk + (t & 3) + 8 * (t >> 2) + 4 * hi;
                float tk = H[t] + b1_lds[k];
                gv[t] = 0.5f * tk * (1.0f + erff(tk * 0.70710678118654752f));
            }
            short8 g0, g1;
            pack_swap16(gv, g0, g1);
            short8 wf0 = ld8(&w2tb[l31 & 15][32 * kblk + 8 * hi]);
            short8 wf1 = ld8(&w2tb[l31 & 15][32 * kblk + 16 + 8 * hi]);
            O2 = __builtin_amdgcn_mfma_f32_32x32x16_bf16(wf0, g0, O2, 0, 0, 0);
            O2 = __builtin_amdgcn_mfma_f32_32x32x16_bf16(wf1, g1, O2, 0, 0, 0);
        }
        __syncthreads();   // Olds attn values fully consumed (P3 done at prior barrier)
        #pragma unroll
        for (int t = 0; t < 8; ++t) {
            const int d = (t & 3) + 8 * (t >> 2) + 4 * hi;   // 0..15 across hi
            Olds[32 * w + l31][d] = O2[t];
        }
    }
    __syncthreads();

    // ---------------- P5: out = o1 + mlp + b2 (q0) ----------------------------
    if (q == 0) {
        float o1[DD];
        #pragma unroll
        for (int i = 0; i < 10; ++i) o1[i] = o1a[r * 10 + i];
        #pragma unroll
        for (int i = 0; i < 6; ++i)  o1[10 + i] = o1b[r * 6 + i];
        float* orow = out + ((size_t)b * NTOK + r) * DD;
        #pragma unroll
        for (int qq = 0; qq < 4; ++qq) {
            float4 bv = ((const float4*)b2)[qq];
            float4 o;
            o.x = o1[4*qq+0] + Olds[r][4*qq+0] + bv.x;
            o.y = o1[4*qq+1] + Olds[r][4*qq+1] + bv.y;
            o.z = o1[4*qq+2] + Olds[r][4*qq+2] + bv.z;
            o.w = o1[4*qq+3] + Olds[r][4*qq+3] + bv.w;
            ((float4*)orow)[qq] = o;
        }
    }
}

extern "C" void kernel_launch(void* const* d_in, const int* in_sizes, int n_in,
                              void* d_out, int out_size, void* d_ws, size_t ws_size,
                              hipStream_t stream) {
    const float* x     = (const float*)d_in[0];
    const float* ln1_g = (const float*)d_in[1];
    const float* ln1_b = (const float*)d_in[2];
    const float* ang   = (const float*)d_in[3];
    const float* ln2_g = (const float*)d_in[4];
    const float* ln2_b = (const float*)d_in[5];
    const float* w1    = (const float*)d_in[6];
    const float* b1    = (const float*)d_in[7];
    const float* w2    = (const float*)d_in[8];
    const float* b2    = (const float*)d_in[9];
    float* out = (float*)d_out;

    const int B = in_sizes[0] / (NTOK * DD);
    hipLaunchKernelGGL(qab_kernel, dim3(B), dim3(BDIM), 0, stream,
                       x, ln1_g, ln1_b, ang, ln2_g, ln2_b, w1, b1, w2, b2, out);
}

// Round 6
// 27.642 us; speedup vs baseline: 3.2634x; 1.0861x over previous
//
#include <hip/hip_runtime.h>
#include <math.h>

#define NTOK 256
#define DD 16
#define BDIM 512

typedef short short8 __attribute__((ext_vector_type(8)));
typedef float f32x16 __attribute__((ext_vector_type(16)));
typedef unsigned int u32;
typedef unsigned long long u64;

__device__ __forceinline__ float safe_acos(float u) {
    return (fabsf(u) <= 1.0f) ? acosf(u) : 0.0f;
}
__device__ __forceinline__ u32 f2bf(float f) {
    u32 u = __float_as_uint(f);
    u += 0x7FFFu + ((u >> 16) & 1u);
    return u >> 16;
}
__device__ __forceinline__ float bf2f(unsigned short h) {
    return __uint_as_float(((u32)h) << 16);
}
struct U128 { u64 a, b; };
__device__ __forceinline__ short8 ld8(const unsigned short* p) {
    U128 t;
    t.a = *(const u64*)(p);
    t.b = *(const u64*)(p + 4);
    return __builtin_bit_cast(short8, t);
}
// pack 16 f32 (reg t -> k-offset pat(t,hi)=(t&3)+8*(t>>2)+4*hi) into two
// fragment short8s with k = 8*hi+e (f0: k 0..15, f1: k 16..31).
// HW-validated in R3/R4 (A-frag and B-frag uses). Swap hazard covered by the
// natural >=4-instr separation from the cvt_pk block.
__device__ __forceinline__ void pack_swap16(f32x16 p, short8& f0, short8& f1) {
    u32 W00, W01, W10, W11, W20, W21, W30, W31;
    asm("v_cvt_pk_bf16_f32 %0, %1, %2" : "=v"(W00) : "v"(p[0]),  "v"(p[1]));
    asm("v_cvt_pk_bf16_f32 %0, %1, %2" : "=v"(W01) : "v"(p[2]),  "v"(p[3]));
    asm("v_cvt_pk_bf16_f32 %0, %1, %2" : "=v"(W10) : "v"(p[4]),  "v"(p[5]));
    asm("v_cvt_pk_bf16_f32 %0, %1, %2" : "=v"(W11) : "v"(p[6]),  "v"(p[7]));
    asm("v_cvt_pk_bf16_f32 %0, %1, %2" : "=v"(W20) : "v"(p[8]),  "v"(p[9]));
    asm("v_cvt_pk_bf16_f32 %0, %1, %2" : "=v"(W21) : "v"(p[10]), "v"(p[11]));
    asm("v_cvt_pk_bf16_f32 %0, %1, %2" : "=v"(W30) : "v"(p[12]), "v"(p[13]));
    asm("v_cvt_pk_bf16_f32 %0, %1, %2" : "=v"(W31) : "v"(p[14]), "v"(p[15]));
    asm("v_permlane32_swap_b32 %0, %1" : "+v"(W00), "+v"(W10));
    asm("v_permlane32_swap_b32 %0, %1" : "+v"(W01), "+v"(W11));
    asm("v_permlane32_swap_b32 %0, %1" : "+v"(W20), "+v"(W30));
    asm("v_permlane32_swap_b32 %0, %1" : "+v"(W21), "+v"(W31));
    struct { u32 x, y, z, w; } i0{W00, W01, W10, W11}, i1{W20, W21, W30, W31};
    f0 = __builtin_bit_cast(short8, i0);
    f1 = __builtin_bit_cast(short8, i1);
}

__global__ __launch_bounds__(BDIM, 4) void qab_kernel(
    const float* __restrict__ x,
    const float* __restrict__ ln1_g, const float* __restrict__ ln1_b,
    const float* __restrict__ angles,
    const float* __restrict__ ln2_g, const float* __restrict__ ln2_b,
    const float* __restrict__ w1, const float* __restrict__ b1,
    const float* __restrict__ w2, const float* __restrict__ b2,
    float* __restrict__ out)
{
    // alignas(16): small float arrays are read with float4 casts -> must be
    // 16B-aligned or ds_read_b128 reads garbage (R5 failure mode #1).
    __shared__ alignas(16) unsigned short a_bf[NTOK][20];   // amplitudes bf16
    __shared__ alignas(16) unsigned short wa_bf[NTOK][20];  // Wa bf16
    __shared__ alignas(16) unsigned short vxT[17][268];     // |Wa|^T + ones row
    __shared__ alignas(16) float W_lds[DD][DD];
    __shared__ alignas(16) unsigned short w1tb[64][20];     // w1^T bf16 [k][e]
    __shared__ alignas(16) unsigned short w2tb[16][68];     // w2^T bf16 [d][k]
    __shared__ alignas(16) float b1_lds[64];
    __shared__ alignas(16) float ln2g_lds[DD];
    __shared__ alignas(16) float ln2b_lds[DD];
    __shared__ alignas(16) float b2_lds[DD];

    const int b   = blockIdx.x;
    const int tid = threadIdx.x;
    const int r   = tid & (NTOK - 1);
    const int q   = tid >> 8;
    const int w   = tid >> 6;
    const int l31 = tid & 31;
    const int hi  = (tid >> 5) & 1;

    // issue residual-x loads early (row = my attention lane-row)
    const float* xres = x + ((size_t)b * NTOK + 32 * w + l31) * DD;
    const float4 xra = *(const float4*)(xres + 4 * hi);       // d = 4hi..4hi+3
    const float4 xrb = *(const float4*)(xres + 8 + 4 * hi);   // d = 8+4hi..

    f32x16 zc;
    #pragma unroll
    for (int t = 0; t < 16; ++t) zc[t] = 0.0f;

    // ---------------- P0: staging (q1) + amplitude chain (q0) ----------------
    if (q == 1) {
        for (int i = r; i < 64 * DD; i += NTOK) {
            w1tb[i & 63][i >> 6] = (unsigned short)f2bf(w1[i]);   // w1^T
            w2tb[i & 15][i >> 4] = (unsigned short)f2bf(w2[i]);   // w2^T
        }
        if (r >= 128 && r < 192) b1_lds[r - 128] = b1[r - 128];
        if (r >= 192 && r < 208) ln2g_lds[r - 192] = ln2_g[r - 192];
        if (r >= 208 && r < 224) ln2b_lds[r - 208] = ln2_b[r - 208];
        if (r >= 224 && r < 240) b2_lds[r - 224] = b2[r - 224];
        vxT[16][r] = 0x3F80;   // ones row -> softmax denominator
        if (r < 16) {
            const int c = r;
            float m[DD];
            #pragma unroll
            for (int rr = 0; rr < DD; ++rr) m[rr] = (rr == c) ? 1.0f : 0.0f;
            #pragma unroll
            for (int s = 0; s < 4; ++s) {
                const int step = 1 << s;
                #pragma unroll
                for (int p = 0; p < 8; ++p) {
                    const int i = ((p >> s) << (s + 1)) | (p & (step - 1));
                    const int j = i + step;
                    float sn, cs;
                    sincosf(angles[s * 8 + p], &sn, &cs);
                    float mi = m[i], mj = m[j];
                    m[i] =  cs * mi + sn * mj;
                    m[j] = -sn * mi + cs * mj;
                }
            }
            #pragma unroll
            for (int rr = 0; rr < DD; ++rr) W_lds[rr][c] = m[rr];
        }
    }

    float amp[DD];
    if (q == 0) {
        const float* xrow = x + ((size_t)b * NTOK + r) * DD;
        float xr[DD];
        #pragma unroll
        for (int qq = 0; qq < 4; ++qq) {
            float4 v = ((const float4*)xrow)[qq];
            xr[4*qq+0] = v.x; xr[4*qq+1] = v.y; xr[4*qq+2] = v.z; xr[4*qq+3] = v.w;
        }
        float mu = 0.0f;
        #pragma unroll
        for (int d = 0; d < DD; ++d) mu += xr[d];
        mu *= (1.0f / DD);
        float var = 0.0f;
        #pragma unroll
        for (int d = 0; d < DD; ++d) { float dv = xr[d] - mu; var += dv * dv; }
        var *= (1.0f / DD);
        float rs = 1.0f / sqrtf(var + 1e-5f);
        float inp[DD];
        #pragma unroll
        for (int d = 0; d < DD; ++d)
            inp[d] = ((xr[d] - mu) * rs * ln1_g[d] + ln1_b[d]) * 0.5f;

        // RBS spherical decomposition (reference fp32 op order — do not alter)
        {
            float a_prev = safe_acos(inp[0]);
            float t = 1.0f, prefix = 1.0f;
            #pragma unroll
            for (int i = 1; i < DD - 1; ++i) {
                float si, ci;
                sincosf(a_prev, &si, &ci);
                amp[i - 1] = prefix * ci;
                prefix *= si;
                float inv = 1.0f / si;
                if (isinf(inv)) inv = copysignf(3.4028234663852886e38f, inv);
                t = t * inv;
                a_prev = safe_acos(inp[i] * t);
            }
            float si, ci;
            sincosf(a_prev, &si, &ci);
            amp[DD - 2] = prefix * ci;
            prefix *= si;
            amp[DD - 1] = prefix;
        }
        u32 aw[8];
        #pragma unroll
        for (int k = 0; k < 8; ++k)
            asm("v_cvt_pk_bf16_f32 %0, %1, %2" : "=v"(aw[k]) : "v"(amp[2*k]), "v"(amp[2*k+1]));
        *(u64*)&a_bf[r][0]  = (u64)aw[0] | ((u64)aw[1] << 32);
        *(u64*)&a_bf[r][4]  = (u64)aw[2] | ((u64)aw[3] << 32);
        *(u64*)&a_bf[r][8]  = (u64)aw[4] | ((u64)aw[5] << 32);
        *(u64*)&a_bf[r][12] = (u64)aw[6] | ((u64)aw[7] << 32);
    }
    __syncthreads();

    // ---------------- P1: Wa = W @ a (d-halves split across q) ----------------
    {
        float av[DD];
        if (q == 0) {
            #pragma unroll
            for (int d = 0; d < DD; ++d) av[d] = amp[d];
        } else {
            short8 t0 = ld8(&a_bf[r][0]);
            short8 t1 = ld8(&a_bf[r][8]);
            #pragma unroll
            for (int e = 0; e < 8; ++e) {
                av[e]     = bf2f((unsigned short)t0[e]);
                av[8 + e] = bf2f((unsigned short)t1[e]);
            }
        }
        const int d0 = q * 8;
        float wav[8];
        #pragma unroll
        for (int dd2 = 0; dd2 < 8; ++dd2) {
            const int d = d0 + dd2;
            float s = 0.0f;
            #pragma unroll
            for (int e = 0; e < DD; ++e) s += W_lds[d][e] * av[e];
            wav[dd2] = s;
            vxT[d][r] = (unsigned short)f2bf(fabsf(s));
        }
        u32 ww[4];
        #pragma unroll
        for (int k = 0; k < 4; ++k)
            asm("v_cvt_pk_bf16_f32 %0, %1, %2" : "=v"(ww[k]) : "v"(wav[2*k]), "v"(wav[2*k+1]));
        *(u64*)&wa_bf[r][d0]     = (u64)ww[0] | ((u64)ww[1] << 32);
        *(u64*)&wa_bf[r][d0 + 4] = (u64)ww[2] | ((u64)ww[3] << 32);
    }
    __syncthreads();
    // ======== everything below is barrier-free and per-wave independent ========

    // ---------------- P2: attention. O^T orientation: lane = token, regs = d --
    const int ncl  = (l31 < 16) ? l31 : 16;   // vx A-frag row clamp (row16 = ones)
    f32x16 Oacc = zc;
    {
        short8 waf = ld8(&wa_bf[w * 32 + l31][8 * hi]);   // B-frag: col i, k = d
        #pragma unroll
        for (int jt = 0; jt < 8; ++jt) {
            short8 af = ld8(&a_bf[jt * 32 + l31][8 * hi]); // A-frag: row j, k = d
            // S: lane holds S[i = 32w + l31][j = 32jt + pat(t,hi)]
            f32x16 S = __builtin_amdgcn_mfma_f32_32x32x16_bf16(af, waf, zc, 0, 0, 0);
            f32x16 pv;
            #pragma unroll
            for (int t = 0; t < 16; ++t) pv[t] = __expf(fabsf(S[t]));  // s in [0,1]
            short8 pb0, pb1;
            pack_swap16(pv, pb0, pb1);                     // B-frags: col i, k = j
            short8 va0 = ld8(&vxT[ncl][jt * 32 + 8 * hi]); // A-frags: row d, k = j
            short8 va1 = ld8(&vxT[ncl][jt * 32 + 16 + 8 * hi]);
            // O_ext^T: lane = token i, reg t -> d = pat(t,hi); rows 16..31 = l
            Oacc = __builtin_amdgcn_mfma_f32_32x32x16_bf16(va0, pb0, Oacc, 0, 0, 0);
            Oacc = __builtin_amdgcn_mfma_f32_32x32x16_bf16(va1, pb1, Oacc, 0, 0, 0);
        }
    }

    // ---------------- P3: residual + LN2, in-register (lane pairs) ------------
    // Oacc[8] = row pat(8,hi) = 16 (hi=0) or 20 (hi=1); rows 16..31 all carry l
    // (clamped ones-row A data) -> no cross-lane broadcast needed.
    const float rl = 1.0f / Oacc[8];
    float o1[8];
    o1[0] = xra.x + Oacc[0] * rl;  o1[1] = xra.y + Oacc[1] * rl;
    o1[2] = xra.z + Oacc[2] * rl;  o1[3] = xra.w + Oacc[3] * rl;
    o1[4] = xrb.x + Oacc[4] * rl;  o1[5] = xrb.y + Oacc[5] * rl;
    o1[6] = xrb.z + Oacc[6] * rl;  o1[7] = xrb.w + Oacc[7] * rl;

    float s8 = 0.0f;
    #pragma unroll
    for (int t = 0; t < 8; ++t) s8 += o1[t];
    float mu2 = (s8 + __shfl_xor(s8, 32, 64)) * (1.0f / DD);
    float v8 = 0.0f;
    #pragma unroll
    for (int t = 0; t < 8; ++t) { float dv = o1[t] - mu2; v8 += dv * dv; }
    float var2 = (v8 + __shfl_xor(v8, 32, 64)) * (1.0f / DD);
    float rs2 = 1.0f / sqrtf(var2 + 1e-5f);

    const float4 g0v = *(const float4*)&ln2g_lds[4 * hi];
    const float4 g1v = *(const float4*)&ln2g_lds[8 + 4 * hi];
    const float4 bb0 = *(const float4*)&ln2b_lds[4 * hi];
    const float4 bb1 = *(const float4*)&ln2b_lds[8 + 4 * hi];
    float h[8];
    h[0] = (o1[0]-mu2)*rs2*g0v.x + bb0.x;  h[1] = (o1[1]-mu2)*rs2*g0v.y + bb0.y;
    h[2] = (o1[2]-mu2)*rs2*g0v.z + bb0.z;  h[3] = (o1[3]-mu2)*rs2*g0v.w + bb0.w;
    h[4] = (o1[4]-mu2)*rs2*g1v.x + bb1.x;  h[5] = (o1[5]-mu2)*rs2*g1v.y + bb1.y;
    h[6] = (o1[6]-mu2)*rs2*g1v.z + bb1.z;  h[7] = (o1[7]-mu2)*rs2*g1v.w + bb1.w;

    // pack h into B-frag (col = token, k = d): 4 cvt_pk + 2 swaps.
    // s_nop guards the VALU->permlane wait-state (opaque to hazard recognizer).
    short8 hB;
    {
        u32 w0, w1u, w2u, w3;
        asm("v_cvt_pk_bf16_f32 %0, %1, %2" : "=v"(w0)  : "v"(h[0]), "v"(h[1]));
        asm("v_cvt_pk_bf16_f32 %0, %1, %2" : "=v"(w1u) : "v"(h[2]), "v"(h[3]));
        asm("v_cvt_pk_bf16_f32 %0, %1, %2" : "=v"(w2u) : "v"(h[4]), "v"(h[5]));
        asm("v_cvt_pk_bf16_f32 %0, %1, %2" : "=v"(w3)  : "v"(h[6]), "v"(h[7]));
        asm("s_nop 1\n\tv_permlane32_swap_b32 %0, %1" : "+v"(w0),  "+v"(w2u));
        asm("s_nop 1\n\tv_permlane32_swap_b32 %0, %1" : "+v"(w1u), "+v"(w3));
        struct { u32 x, y, z, w; } hw{w0, w1u, w2u, w3};
        hB = __builtin_bit_cast(short8, hw);
    }

    // ---------------- P4: MLP via MFMA, all in lane=token orientation ---------
    const int dcl = (l31 < 15) ? l31 : 15;   // w2 A-frag row clamp
    f32x16 O2 = zc;
    {   // init useful regs (t<8) with b2
        const float4 c0 = *(const float4*)&b2_lds[4 * hi];
        const float4 c1 = *(const float4*)&b2_lds[8 + 4 * hi];
        O2[0] = c0.x; O2[1] = c0.y; O2[2] = c0.z; O2[3] = c0.w;
        O2[4] = c1.x; O2[5] = c1.y; O2[6] = c1.z; O2[7] = c1.w;
    }
    #pragma unroll
    for (int kblk = 0; kblk < 2; ++kblk) {
        // C-init with b1 (reg t -> k = 32kblk + pat(t,hi))
        f32x16 Hc;
        {
            const float* bp = &b1_lds[32 * kblk];
            const float4 c0 = *(const float4*)(bp + 4 * hi);
            const float4 c1 = *(const float4*)(bp + 8 + 4 * hi);
            const float4 c2 = *(const float4*)(bp + 16 + 4 * hi);
            const float4 c3 = *(const float4*)(bp + 24 + 4 * hi);
            Hc[0]=c0.x; Hc[1]=c0.y; Hc[2]=c0.z; Hc[3]=c0.w;
            Hc[4]=c1.x; Hc[5]=c1.y; Hc[6]=c1.z; Hc[7]=c1.w;
            Hc[8]=c2.x; Hc[9]=c2.y; Hc[10]=c2.z; Hc[11]=c2.w;
            Hc[12]=c3.x; Hc[13]=c3.y; Hc[14]=c3.z; Hc[15]=c3.w;
        }
        short8 w1f = ld8(&w1tb[32 * kblk + l31][8 * hi]);  // A-frag: row k, k-dim d
        // H^T: lane = token, reg t -> hidden k = 32kblk + pat(t,hi)
        f32x16 H = __builtin_amdgcn_mfma_f32_32x32x16_bf16(w1f, hB, Hc, 0, 0, 0);
        f32x16 gv;
        #pragma unroll
        for (int t = 0; t < 16; ++t)
            gv[t] = 0.5f * H[t] * (1.0f + erff(H[t] * 0.70710678118654752f));
        short8 gb0, gb1;
        pack_swap16(gv, gb0, gb1);                          // B-frags: col tok, k = hidden
        short8 w2f0 = ld8(&w2tb[dcl][32 * kblk + 8 * hi]);  // A-frags: row d_out
        short8 w2f1 = ld8(&w2tb[dcl][32 * kblk + 16 + 8 * hi]);
        O2 = __builtin_amdgcn_mfma_f32_32x32x16_bf16(w2f0, gb0, O2, 0, 0, 0);
        O2 = __builtin_amdgcn_mfma_f32_32x32x16_bf16(w2f1, gb1, O2, 0, 0, 0);
    }

    // ---------------- P5: out = o1 + O2 (+b2 already in O2), direct store -----
    {
        float* orow = out + ((size_t)b * NTOK + 32 * w + l31) * DD;
        float4 oa, ob;
        oa.x = o1[0] + O2[0]; oa.y = o1[1] + O2[1];
        oa.z = o1[2] + O2[2]; oa.w = o1[3] + O2[3];
        ob.x = o1[4] + O2[4]; ob.y = o1[5] + O2[5];
        ob.z = o1[6] + O2[6]; ob.w = o1[7] + O2[7];
        *(float4*)(orow + 4 * hi) = oa;
        *(float4*)(orow + 8 + 4 * hi) = ob;
    }
}

extern "C" void kernel_launch(void* const* d_in, const int* in_sizes, int n_in,
                              void* d_out, int out_size, void* d_ws, size_t ws_size,
                              hipStream_t stream) {
    const float* x     = (const float*)d_in[0];
    const float* ln1_g = (const float*)d_in[1];
    const float* ln1_b = (const float*)d_in[2];
    const float* ang   = (const float*)d_in[3];
    const float* ln2_g = (const float*)d_in[4];
    const float* ln2_b = (const float*)d_in[5];
    const float* w1    = (const float*)d_in[6];
    const float* b1    = (const float*)d_in[7];
    const float* w2    = (const float*)d_in[8];
    const float* b2    = (const float*)d_in[9];
    float* out = (float*)d_out;

    const int B = in_sizes[0] / (NTOK * DD);
    hipLaunchKernelGGL(qab_kernel, dim3(B), dim3(BDIM), 0, stream,
                       x, ln1_g, ln1_b, ang, ln2_g, ln2_b, w1, b1, w2, b2, out);
}

// Round 7
// 20.240 us; speedup vs baseline: 4.4568x; 1.3657x over previous
//
#include <hip/hip_runtime.h>
#include <math.h>

#define NTOK 256
#define DD 16
#define BDIM 512

typedef short short8 __attribute__((ext_vector_type(8)));
typedef float f32x16 __attribute__((ext_vector_type(16)));
typedef unsigned int u32;
typedef unsigned long long u64;

__device__ __forceinline__ u32 f2bf(float f) {
    u32 u = __float_as_uint(f);
    u += 0x7FFFu + ((u >> 16) & 1u);
    return u >> 16;
}
struct U128 { u64 a, b; };
__device__ __forceinline__ short8 ld8(const unsigned short* p) {
    U128 t;
    t.a = *(const u64*)(p);
    t.b = *(const u64*)(p + 4);
    return __builtin_bit_cast(short8, t);
}
// pack 16 f32 (reg t -> k-offset pat(t,hi)=(t&3)+8*(t>>2)+4*hi) into two
// fragment short8s with k = 8*hi+e (f0: k 0..15, f1: k 16..31). HW-validated R3/R4/R6.
__device__ __forceinline__ void pack_swap16(f32x16 p, short8& f0, short8& f1) {
    u32 W00, W01, W10, W11, W20, W21, W30, W31;
    asm("v_cvt_pk_bf16_f32 %0, %1, %2" : "=v"(W00) : "v"(p[0]),  "v"(p[1]));
    asm("v_cvt_pk_bf16_f32 %0, %1, %2" : "=v"(W01) : "v"(p[2]),  "v"(p[3]));
    asm("v_cvt_pk_bf16_f32 %0, %1, %2" : "=v"(W10) : "v"(p[4]),  "v"(p[5]));
    asm("v_cvt_pk_bf16_f32 %0, %1, %2" : "=v"(W11) : "v"(p[6]),  "v"(p[7]));
    asm("v_cvt_pk_bf16_f32 %0, %1, %2" : "=v"(W20) : "v"(p[8]),  "v"(p[9]));
    asm("v_cvt_pk_bf16_f32 %0, %1, %2" : "=v"(W21) : "v"(p[10]), "v"(p[11]));
    asm("v_cvt_pk_bf16_f32 %0, %1, %2" : "=v"(W30) : "v"(p[12]), "v"(p[13]));
    asm("v_cvt_pk_bf16_f32 %0, %1, %2" : "=v"(W31) : "v"(p[14]), "v"(p[15]));
    asm("v_permlane32_swap_b32 %0, %1" : "+v"(W00), "+v"(W10));
    asm("v_permlane32_swap_b32 %0, %1" : "+v"(W01), "+v"(W11));
    asm("v_permlane32_swap_b32 %0, %1" : "+v"(W20), "+v"(W30));
    asm("v_permlane32_swap_b32 %0, %1" : "+v"(W21), "+v"(W31));
    struct { u32 x, y, z, w; } i0{W00, W01, W10, W11}, i1{W20, W21, W30, W31};
    f0 = __builtin_bit_cast(short8, i0);
    f1 = __builtin_bit_cast(short8, i1);
}
// exact-GELU via Abramowitz-Stegun 7.1.26 erf (|err| <= 1.5e-7)
__device__ __forceinline__ float gelu_erf(float v) {
    float xx = v * 0.70710678118654752f;
    float ax = fabsf(xx);
    float t = __builtin_amdgcn_rcpf(__builtin_fmaf(0.3275911f, ax, 1.0f));
    float poly = t * (0.254829592f + t * (-0.284496736f + t * (1.421413741f
               + t * (-1.453152027f + t * 1.061405429f))));
    float r = 1.0f - poly * __expf(-ax * ax);
    float e = copysignf(r, xx);
    return 0.5f * v * (1.0f + e);
}

__global__ __launch_bounds__(BDIM, 4) void qab_kernel(
    const float* __restrict__ x,
    const float* __restrict__ ln1_g, const float* __restrict__ ln1_b,
    const float* __restrict__ angles,
    const float* __restrict__ ln2_g, const float* __restrict__ ln2_b,
    const float* __restrict__ w1, const float* __restrict__ b1,
    const float* __restrict__ w2, const float* __restrict__ b2,
    float* __restrict__ out)
{
    __shared__ alignas(16) unsigned short a_bf[NTOK][20];   // amplitudes bf16
    __shared__ alignas(16) unsigned short wa_bf[NTOK][20];  // Wa bf16
    __shared__ alignas(16) unsigned short vxT[17][268];     // |Wa|^T + ones row
    __shared__ alignas(16) unsigned short w1tb[64][20];     // w1^T bf16 [k][e]
    __shared__ alignas(16) unsigned short w2tb[16][68];     // w2^T bf16 [d][k]
    __shared__ alignas(16) float b1_lds[64];
    __shared__ alignas(16) float ln2g_lds[DD];
    __shared__ alignas(16) float ln2b_lds[DD];
    __shared__ alignas(16) float b2_lds[DD];

    const int b    = blockIdx.x;
    const int tid  = threadIdx.x;
    const int r    = tid & (NTOK - 1);
    const int q    = tid >> 8;
    const int w    = tid >> 6;
    const int l31  = tid & 31;
    const int hi   = (tid >> 5) & 1;
    const int lane = tid & 63;

    // issue residual-x loads early (row = my attention lane-row)
    const float* xres = x + ((size_t)b * NTOK + 32 * w + l31) * DD;
    const float4 xra = *(const float4*)(xres + 4 * hi);
    const float4 xrb = *(const float4*)(xres + 8 + 4 * hi);

    f32x16 zc;
    #pragma unroll
    for (int t = 0; t < 16; ++t) zc[t] = 0.0f;

    // ---------------- P0: LN1 + amp chain (ALL threads; row r redundant x2) ---
    float amp[DD];
    {
        const float* xrow = x + ((size_t)b * NTOK + r) * DD;
        float xr[DD];
        #pragma unroll
        for (int qq = 0; qq < 4; ++qq) {
            float4 v = ((const float4*)xrow)[qq];
            xr[4*qq+0] = v.x; xr[4*qq+1] = v.y; xr[4*qq+2] = v.z; xr[4*qq+3] = v.w;
        }
        float mu = 0.0f;
        #pragma unroll
        for (int d = 0; d < DD; ++d) mu += xr[d];
        mu *= (1.0f / DD);
        float var = 0.0f;
        #pragma unroll
        for (int d = 0; d < DD; ++d) { float dv = xr[d] - mu; var += dv * dv; }
        var *= (1.0f / DD);
        float rs = 1.0f / sqrtf(var + 1e-5f);
        float inp[DD];
        #pragma unroll
        for (int d = 0; d < DD; ++d)
            inp[d] = ((xr[d] - mu) * rs * ln1_g[d] + ln1_b[d]) * 0.5f;

        // RBS chain without acos/sincos: cos(acos(u))=u, sin=sqrt(1-u^2).
        // safe_acos |u|>1 -> alpha=0 -> (c,s)=(1,0). 1/s: +inf -> FLT_MAX.
        float u0 = inp[0];
        bool ok = fabsf(u0) <= 1.0f;
        float c = ok ? u0 : 1.0f;
        float s = ok ? __builtin_amdgcn_sqrtf(__builtin_fmaf(-u0, u0, 1.0f)) : 0.0f;
        float t = 1.0f, prefix = 1.0f;
        #pragma unroll
        for (int i = 1; i < DD - 1; ++i) {
            amp[i - 1] = prefix * c;
            prefix *= s;
            float inv = __builtin_amdgcn_rcpf(s);
            if (isinf(inv)) inv = 3.4028234663852886e38f;   // sin(alpha) >= 0
            t = t * inv;
            float u = inp[i] * t;
            ok = fabsf(u) <= 1.0f;
            c = ok ? u : 1.0f;
            s = ok ? __builtin_amdgcn_sqrtf(__builtin_fmaf(-u, u, 1.0f)) : 0.0f;
        }
        amp[DD - 2] = prefix * c;
        amp[DD - 1] = prefix * s;
    }

    if (q == 0) {
        // ---- write a_bf + stage weights/consts ----
        u32 aw[8];
        #pragma unroll
        for (int k = 0; k < 8; ++k)
            asm("v_cvt_pk_bf16_f32 %0, %1, %2" : "=v"(aw[k]) : "v"(amp[2*k]), "v"(amp[2*k+1]));
        *(u64*)&a_bf[r][0]  = (u64)aw[0] | ((u64)aw[1] << 32);
        *(u64*)&a_bf[r][4]  = (u64)aw[2] | ((u64)aw[3] << 32);
        *(u64*)&a_bf[r][8]  = (u64)aw[4] | ((u64)aw[5] << 32);
        *(u64*)&a_bf[r][12] = (u64)aw[6] | ((u64)aw[7] << 32);
        for (int i = r; i < 64 * DD; i += NTOK) {
            w1tb[i & 63][i >> 6] = (unsigned short)f2bf(w1[i]);   // w1^T
            w2tb[i & 15][i >> 4] = (unsigned short)f2bf(w2[i]);   // w2^T
        }
        if (r >= 128 && r < 192) b1_lds[r - 128] = b1[r - 128];
        if (r >= 192 && r < 208) ln2g_lds[r - 192] = ln2_g[r - 192];
        if (r >= 208 && r < 224) ln2b_lds[r - 208] = ln2_b[r - 208];
        if (r >= 224 && r < 240) b2_lds[r - 224] = b2[r - 224];
        vxT[16][r] = 0x3F80;   // ones row -> softmax denominator
    } else {
        // ---- Wa = butterfly rotations applied directly to amp (in place) ----
        float sn_l = 0.0f, cs_l = 0.0f;
        if (lane < 32) sincosf(angles[lane], &sn_l, &cs_l);
        #pragma unroll
        for (int s = 0; s < 4; ++s) {
            const int step = 1 << s;
            #pragma unroll
            for (int p = 0; p < 8; ++p) {
                const int i = ((p >> s) << (s + 1)) | (p & (step - 1));
                const int j = i + step;
                float sn = __shfl(sn_l, s * 8 + p, 64);   // v_readlane broadcast
                float cs = __shfl(cs_l, s * 8 + p, 64);
                float vi = amp[i], vj = amp[j];
                amp[i] =  cs * vi + sn * vj;
                amp[j] = -sn * vi + cs * vj;
            }
        }
        u32 ww[8];
        #pragma unroll
        for (int k = 0; k < 8; ++k)
            asm("v_cvt_pk_bf16_f32 %0, %1, %2" : "=v"(ww[k]) : "v"(amp[2*k]), "v"(amp[2*k+1]));
        *(u64*)&wa_bf[r][0]  = (u64)ww[0] | ((u64)ww[1] << 32);
        *(u64*)&wa_bf[r][4]  = (u64)ww[2] | ((u64)ww[3] << 32);
        *(u64*)&wa_bf[r][8]  = (u64)ww[4] | ((u64)ww[5] << 32);
        *(u64*)&wa_bf[r][12] = (u64)ww[6] | ((u64)ww[7] << 32);
        #pragma unroll
        for (int d = 0; d < DD; ++d)
            vxT[d][r] = (unsigned short)f2bf(fabsf(amp[d]));
    }
    __syncthreads();
    // ======== everything below is barrier-free and per-wave independent ========

    // ---------------- P2: attention. O^T orientation: lane = token, regs = d --
    const int ncl = (l31 < 16) ? l31 : 16;   // vx A-frag row clamp (row16 = ones)
    f32x16 Oacc = zc;
    {
        short8 waf = ld8(&wa_bf[w * 32 + l31][8 * hi]);   // B-frag: col i, k = d
        #pragma unroll
        for (int jt = 0; jt < 8; ++jt) {
            short8 af = ld8(&a_bf[jt * 32 + l31][8 * hi]); // A-frag: row j, k = d
            // S: lane holds S[i = 32w + l31][j = 32jt + pat(t,hi)]
            f32x16 S = __builtin_amdgcn_mfma_f32_32x32x16_bf16(af, waf, zc, 0, 0, 0);
            f32x16 pv;
            #pragma unroll
            for (int t = 0; t < 16; ++t) pv[t] = __expf(fabsf(S[t]));  // s in [0,1]
            short8 pb0, pb1;
            pack_swap16(pv, pb0, pb1);                     // B-frags: col i, k = j
            short8 va0 = ld8(&vxT[ncl][jt * 32 + 8 * hi]); // A-frags: row d, k = j
            short8 va1 = ld8(&vxT[ncl][jt * 32 + 16 + 8 * hi]);
            Oacc = __builtin_amdgcn_mfma_f32_32x32x16_bf16(va0, pb0, Oacc, 0, 0, 0);
            Oacc = __builtin_amdgcn_mfma_f32_32x32x16_bf16(va1, pb1, Oacc, 0, 0, 0);
        }
    }

    // ---------------- P3: residual + LN2, in-register (lane pairs) ------------
    // Oacc[8] = row 16 (hi=0) / 20 (hi=1); rows 16..31 all = l (clamped ones-row)
    const float rl = 1.0f / Oacc[8];
    float o1[8];
    o1[0] = xra.x + Oacc[0] * rl;  o1[1] = xra.y + Oacc[1] * rl;
    o1[2] = xra.z + Oacc[2] * rl;  o1[3] = xra.w + Oacc[3] * rl;
    o1[4] = xrb.x + Oacc[4] * rl;  o1[5] = xrb.y + Oacc[5] * rl;
    o1[6] = xrb.z + Oacc[6] * rl;  o1[7] = xrb.w + Oacc[7] * rl;

    float s8 = 0.0f;
    #pragma unroll
    for (int t = 0; t < 8; ++t) s8 += o1[t];
    float mu2 = (s8 + __shfl_xor(s8, 32, 64)) * (1.0f / DD);
    float v8 = 0.0f;
    #pragma unroll
    for (int t = 0; t < 8; ++t) { float dv = o1[t] - mu2; v8 += dv * dv; }
    float var2 = (v8 + __shfl_xor(v8, 32, 64)) * (1.0f / DD);
    float rs2 = 1.0f / sqrtf(var2 + 1e-5f);

    const float4 g0v = *(const float4*)&ln2g_lds[4 * hi];
    const float4 g1v = *(const float4*)&ln2g_lds[8 + 4 * hi];
    const float4 bb0 = *(const float4*)&ln2b_lds[4 * hi];
    const float4 bb1 = *(const float4*)&ln2b_lds[8 + 4 * hi];
    float h[8];
    h[0] = (o1[0]-mu2)*rs2*g0v.x + bb0.x;  h[1] = (o1[1]-mu2)*rs2*g0v.y + bb0.y;
    h[2] = (o1[2]-mu2)*rs2*g0v.z + bb0.z;  h[3] = (o1[3]-mu2)*rs2*g0v.w + bb0.w;
    h[4] = (o1[4]-mu2)*rs2*g1v.x + bb1.x;  h[5] = (o1[5]-mu2)*rs2*g1v.y + bb1.y;
    h[6] = (o1[6]-mu2)*rs2*g1v.z + bb1.z;  h[7] = (o1[7]-mu2)*rs2*g1v.w + bb1.w;

    short8 hB;   // B-frag (col = token, k = d)
    {
        u32 w0, w1u, w2u, w3;
        asm("v_cvt_pk_bf16_f32 %0, %1, %2" : "=v"(w0)  : "v"(h[0]), "v"(h[1]));
        asm("v_cvt_pk_bf16_f32 %0, %1, %2" : "=v"(w1u) : "v"(h[2]), "v"(h[3]));
        asm("v_cvt_pk_bf16_f32 %0, %1, %2" : "=v"(w2u) : "v"(h[4]), "v"(h[5]));
        asm("v_cvt_pk_bf16_f32 %0, %1, %2" : "=v"(w3)  : "v"(h[6]), "v"(h[7]));
        asm("s_nop 1\n\tv_permlane32_swap_b32 %0, %1" : "+v"(w0),  "+v"(w2u));
        asm("s_nop 1\n\tv_permlane32_swap_b32 %0, %1" : "+v"(w1u), "+v"(w3));
        struct { u32 x, y, z, w; } hw{w0, w1u, w2u, w3};
        hB = __builtin_bit_cast(short8, hw);
    }

    // ---------------- P4: MLP via MFMA, all in lane=token orientation ---------
    const int dcl = (l31 < 15) ? l31 : 15;   // w2 A-frag row clamp
    f32x16 O2 = zc;
    {
        const float4 c0 = *(const float4*)&b2_lds[4 * hi];
        const float4 c1 = *(const float4*)&b2_lds[8 + 4 * hi];
        O2[0] = c0.x; O2[1] = c0.y; O2[2] = c0.z; O2[3] = c0.w;
        O2[4] = c1.x; O2[5] = c1.y; O2[6] = c1.z; O2[7] = c1.w;
    }
    #pragma unroll
    for (int kblk = 0; kblk < 2; ++kblk) {
        f32x16 Hc;
        {
            const float* bp = &b1_lds[32 * kblk];
            const float4 c0 = *(const float4*)(bp + 4 * hi);
            const float4 c1 = *(const float4*)(bp + 8 + 4 * hi);
            const float4 c2 = *(const float4*)(bp + 16 + 4 * hi);
            const float4 c3 = *(const float4*)(bp + 24 + 4 * hi);
            Hc[0]=c0.x; Hc[1]=c0.y; Hc[2]=c0.z; Hc[3]=c0.w;
            Hc[4]=c1.x; Hc[5]=c1.y; Hc[6]=c1.z; Hc[7]=c1.w;
            Hc[8]=c2.x; Hc[9]=c2.y; Hc[10]=c2.z; Hc[11]=c2.w;
            Hc[12]=c3.x; Hc[13]=c3.y; Hc[14]=c3.z; Hc[15]=c3.w;
        }
        short8 w1f = ld8(&w1tb[32 * kblk + l31][8 * hi]);
        f32x16 H = __builtin_amdgcn_mfma_f32_32x32x16_bf16(w1f, hB, Hc, 0, 0, 0);
        f32x16 gv;
        #pragma unroll
        for (int t = 0; t < 16; ++t) gv[t] = gelu_erf(H[t]);
        short8 gb0, gb1;
        pack_swap16(gv, gb0, gb1);
        short8 w2f0 = ld8(&w2tb[dcl][32 * kblk + 8 * hi]);
        short8 w2f1 = ld8(&w2tb[dcl][32 * kblk + 16 + 8 * hi]);
        O2 = __builtin_amdgcn_mfma_f32_32x32x16_bf16(w2f0, gb0, O2, 0, 0, 0);
        O2 = __builtin_amdgcn_mfma_f32_32x32x16_bf16(w2f1, gb1, O2, 0, 0, 0);
    }

    // ---------------- P5: out = o1 + O2 (+b2 already in O2), direct store -----
    {
        float* orow = out + ((size_t)b * NTOK + 32 * w + l31) * DD;
        float4 oa, ob;
        oa.x = o1[0] + O2[0]; oa.y = o1[1] + O2[1];
        oa.z = o1[2] + O2[2]; oa.w = o1[3] + O2[3];
        ob.x = o1[4] + O2[4]; ob.y = o1[5] + O2[5];
        ob.z = o1[6] + O2[6]; ob.w = o1[7] + O2[7];
        *(float4*)(orow + 4 * hi) = oa;
        *(float4*)(orow + 8 + 4 * hi) = ob;
    }
}

extern "C" void kernel_launch(void* const* d_in, const int* in_sizes, int n_in,
                              void* d_out, int out_size, void* d_ws, size_t ws_size,
                              hipStream_t stream) {
    const float* x     = (const float*)d_in[0];
    const float* ln1_g = (const float*)d_in[1];
    const float* ln1_b = (const float*)d_in[2];
    const float* ang   = (const float*)d_in[3];
    const float* ln2_g = (const float*)d_in[4];
    const float* ln2_b = (const float*)d_in[5];
    const float* w1    = (const float*)d_in[6];
    const float* b1    = (const float*)d_in[7];
    const float* w2    = (const float*)d_in[8];
    const float* b2    = (const float*)d_in[9];
    float* out = (float*)d_out;

    const int B = in_sizes[0] / (NTOK * DD);
    hipLaunchKernelGGL(qab_kernel, dim3(B), dim3(BDIM), 0, stream,
                       x, ln1_g, ln1_b, ang, ln2_g, ln2_b, w1, b1, w2, b2, out);
}

// Round 8
// 20.213 us; speedup vs baseline: 4.4628x; 1.0013x over previous
//
#include <hip/hip_runtime.h>
#include <math.h>

#define NTOK 256
#define DD 16
#define BDIM 512

typedef short short8 __attribute__((ext_vector_type(8)));
typedef float f32x16 __attribute__((ext_vector_type(16)));
typedef unsigned int u32;
typedef unsigned long long u64;

__device__ __forceinline__ u32 f2bf(float f) {
    u32 u = __float_as_uint(f);
    u += 0x7FFFu + ((u >> 16) & 1u);
    return u >> 16;
}
struct U128 { u64 a, b; };
__device__ __forceinline__ short8 ld8(const unsigned short* p) {
    U128 t;
    t.a = *(const u64*)(p);
    t.b = *(const u64*)(p + 4);
    return __builtin_bit_cast(short8, t);
}
// pack 16 f32 (reg t -> k-offset pat(t,hi)=(t&3)+8*(t>>2)+4*hi) into two
// fragment short8s with k = 8*hi+e (f0: k 0..15, f1: k 16..31). HW-validated R3/R4/R6.
__device__ __forceinline__ void pack_swap16(f32x16 p, short8& f0, short8& f1) {
    u32 W00, W01, W10, W11, W20, W21, W30, W31;
    asm("v_cvt_pk_bf16_f32 %0, %1, %2" : "=v"(W00) : "v"(p[0]),  "v"(p[1]));
    asm("v_cvt_pk_bf16_f32 %0, %1, %2" : "=v"(W01) : "v"(p[2]),  "v"(p[3]));
    asm("v_cvt_pk_bf16_f32 %0, %1, %2" : "=v"(W10) : "v"(p[4]),  "v"(p[5]));
    asm("v_cvt_pk_bf16_f32 %0, %1, %2" : "=v"(W11) : "v"(p[6]),  "v"(p[7]));
    asm("v_cvt_pk_bf16_f32 %0, %1, %2" : "=v"(W20) : "v"(p[8]),  "v"(p[9]));
    asm("v_cvt_pk_bf16_f32 %0, %1, %2" : "=v"(W21) : "v"(p[10]), "v"(p[11]));
    asm("v_cvt_pk_bf16_f32 %0, %1, %2" : "=v"(W30) : "v"(p[12]), "v"(p[13]));
    asm("v_cvt_pk_bf16_f32 %0, %1, %2" : "=v"(W31) : "v"(p[14]), "v"(p[15]));
    asm("v_permlane32_swap_b32 %0, %1" : "+v"(W00), "+v"(W10));
    asm("v_permlane32_swap_b32 %0, %1" : "+v"(W01), "+v"(W11));
    asm("v_permlane32_swap_b32 %0, %1" : "+v"(W20), "+v"(W30));
    asm("v_permlane32_swap_b32 %0, %1" : "+v"(W21), "+v"(W31));
    struct { u32 x, y, z, w; } i0{W00, W01, W10, W11}, i1{W20, W21, W30, W31};
    f0 = __builtin_bit_cast(short8, i0);
    f1 = __builtin_bit_cast(short8, i1);
}
// exact-GELU via Abramowitz-Stegun 7.1.26 erf (|err| <= 1.5e-7)
__device__ __forceinline__ float gelu_erf(float v) {
    float xx = v * 0.70710678118654752f;
    float ax = fabsf(xx);
    float t = __builtin_amdgcn_rcpf(__builtin_fmaf(0.3275911f, ax, 1.0f));
    float poly = t * (0.254829592f + t * (-0.284496736f + t * (1.421413741f
               + t * (-1.453152027f + t * 1.061405429f))));
    float r = 1.0f - poly * __expf(-ax * ax);
    float e = copysignf(r, xx);
    return 0.5f * v * (1.0f + e);
}

__global__ __launch_bounds__(BDIM, 4) void qab_kernel(
    const float* __restrict__ x,
    const float* __restrict__ ln1_g, const float* __restrict__ ln1_b,
    const float* __restrict__ angles,
    const float* __restrict__ ln2_g, const float* __restrict__ ln2_b,
    const float* __restrict__ w1, const float* __restrict__ b1,
    const float* __restrict__ w2, const float* __restrict__ b2,
    float* __restrict__ out)
{
    __shared__ alignas(16) unsigned short a_bf[NTOK][20];   // amplitudes bf16
    __shared__ alignas(16) unsigned short wa_bf[NTOK][20];  // Wa bf16
    __shared__ alignas(16) unsigned short vxT[17][268];     // |Wa|^T + ones row
    __shared__ alignas(16) unsigned short w1tb[64][20];     // w1^T bf16 [k][e]
    __shared__ alignas(16) unsigned short w2tb[16][68];     // w2^T bf16 [d][k]
    __shared__ alignas(16) float b1_lds[64];
    __shared__ alignas(16) float ln2g_lds[DD];
    __shared__ alignas(16) float ln2b_lds[DD];
    __shared__ alignas(16) float b2_lds[DD];

    const int b    = blockIdx.x;
    const int tid  = threadIdx.x;
    const int r    = tid & (NTOK - 1);
    const int q    = tid >> 8;
    const int w    = tid >> 6;
    const int l31  = tid & 31;
    const int hi   = (tid >> 5) & 1;
    const int lane = tid & 63;

    // issue residual-x loads early (row = my attention lane-row)
    const float* xres = x + ((size_t)b * NTOK + 32 * w + l31) * DD;
    const float4 xra = *(const float4*)(xres + 4 * hi);
    const float4 xrb = *(const float4*)(xres + 8 + 4 * hi);

    f32x16 zc;
    #pragma unroll
    for (int t = 0; t < 16; ++t) zc[t] = 0.0f;

    // ---------------- P0: LN1 + amp chain (ALL threads; row r redundant x2) ---
    // Spherical decomposition reconstructs its input: in-range amp[i] = inp[i];
    // only the sin-product prefix matters, tracked as its SQUARE P (p = sqrt(P)).
    //   ok = inp[i]^2 <= P ; amp[i] = ok ? inp[i] : sqrt(P) ; P = ok ? P-inp^2 : 0
    // Clamp semantics identical to safe_acos path (amp=p then all-zeros).
    // Serial chain = 15 fma (sqrt hangs off-chain), vs R7's 15x(rcp+sqrt+fix).
    float amp[DD];
    {
        const float* xrow = x + ((size_t)b * NTOK + r) * DD;
        float xr[DD];
        #pragma unroll
        for (int qq = 0; qq < 4; ++qq) {
            float4 v = ((const float4*)xrow)[qq];
            xr[4*qq+0] = v.x; xr[4*qq+1] = v.y; xr[4*qq+2] = v.z; xr[4*qq+3] = v.w;
        }
        float mu = 0.0f;
        #pragma unroll
        for (int d = 0; d < DD; ++d) mu += xr[d];
        mu *= (1.0f / DD);
        float var = 0.0f;
        #pragma unroll
        for (int d = 0; d < DD; ++d) { float dv = xr[d] - mu; var += dv * dv; }
        var *= (1.0f / DD);
        float rs = 1.0f / sqrtf(var + 1e-5f);
        float inp[DD];
        #pragma unroll
        for (int d = 0; d < DD; ++d)
            inp[d] = ((xr[d] - mu) * rs * ln1_g[d] + ln1_b[d]) * 0.5f;

        float P = 1.0f;
        #pragma unroll
        for (int i = 0; i < DD - 1; ++i) {
            float v = inp[i];
            float v2 = v * v;
            bool ok = v2 <= P;
            amp[i] = ok ? v : __builtin_amdgcn_sqrtf(P);
            P = ok ? __builtin_fmaf(-v, v, P) : 0.0f;
        }
        amp[DD - 1] = __builtin_amdgcn_sqrtf(P);
    }

    if (q == 0) {
        // ---- write a_bf + stage weights/consts ----
        u32 aw[8];
        #pragma unroll
        for (int k = 0; k < 8; ++k)
            asm("v_cvt_pk_bf16_f32 %0, %1, %2" : "=v"(aw[k]) : "v"(amp[2*k]), "v"(amp[2*k+1]));
        *(u64*)&a_bf[r][0]  = (u64)aw[0] | ((u64)aw[1] << 32);
        *(u64*)&a_bf[r][4]  = (u64)aw[2] | ((u64)aw[3] << 32);
        *(u64*)&a_bf[r][8]  = (u64)aw[4] | ((u64)aw[5] << 32);
        *(u64*)&a_bf[r][12] = (u64)aw[6] | ((u64)aw[7] << 32);
        for (int i = r; i < 64 * DD; i += NTOK) {
            w1tb[i & 63][i >> 6] = (unsigned short)f2bf(w1[i]);   // w1^T
            w2tb[i & 15][i >> 4] = (unsigned short)f2bf(w2[i]);   // w2^T
        }
        if (r >= 128 && r < 192) b1_lds[r - 128] = b1[r - 128];
        if (r >= 192 && r < 208) ln2g_lds[r - 192] = ln2_g[r - 192];
        if (r >= 208 && r < 224) ln2b_lds[r - 208] = ln2_b[r - 208];
        if (r >= 224 && r < 240) b2_lds[r - 224] = b2[r - 224];
        vxT[16][r] = 0x3F80;   // ones row -> softmax denominator
    } else {
        // ---- Wa = butterfly rotations applied directly to amp (in place) ----
        float sn_l = 0.0f, cs_l = 0.0f;
        if (lane < 32) __sincosf(angles[lane], &sn_l, &cs_l);
        #pragma unroll
        for (int s = 0; s < 4; ++s) {
            const int step = 1 << s;
            #pragma unroll
            for (int p = 0; p < 8; ++p) {
                const int i = ((p >> s) << (s + 1)) | (p & (step - 1));
                const int j = i + step;
                float sn = __shfl(sn_l, s * 8 + p, 64);   // v_readlane broadcast
                float cs = __shfl(cs_l, s * 8 + p, 64);
                float vi = amp[i], vj = amp[j];
                amp[i] =  cs * vi + sn * vj;
                amp[j] = -sn * vi + cs * vj;
            }
        }
        u32 ww[8];
        #pragma unroll
        for (int k = 0; k < 8; ++k)
            asm("v_cvt_pk_bf16_f32 %0, %1, %2" : "=v"(ww[k]) : "v"(amp[2*k]), "v"(amp[2*k+1]));
        *(u64*)&wa_bf[r][0]  = (u64)ww[0] | ((u64)ww[1] << 32);
        *(u64*)&wa_bf[r][4]  = (u64)ww[2] | ((u64)ww[3] << 32);
        *(u64*)&wa_bf[r][8]  = (u64)ww[4] | ((u64)ww[5] << 32);
        *(u64*)&wa_bf[r][12] = (u64)ww[6] | ((u64)ww[7] << 32);
        #pragma unroll
        for (int d = 0; d < DD; ++d)
            vxT[d][r] = (unsigned short)f2bf(fabsf(amp[d]));
    }
    __syncthreads();
    // ======== everything below is barrier-free and per-wave independent ========

    // ---------------- P2: attention. O^T orientation: lane = token, regs = d --
    const int ncl = (l31 < 16) ? l31 : 16;   // vx A-frag row clamp (row16 = ones)
    f32x16 Oacc = zc;
    {
        short8 waf = ld8(&wa_bf[w * 32 + l31][8 * hi]);   // B-frag: col i, k = d
        #pragma unroll
        for (int jt = 0; jt < 8; ++jt) {
            short8 af = ld8(&a_bf[jt * 32 + l31][8 * hi]); // A-frag: row j, k = d
            // S: lane holds S[i = 32w + l31][j = 32jt + pat(t,hi)]
            f32x16 S = __builtin_amdgcn_mfma_f32_32x32x16_bf16(af, waf, zc, 0, 0, 0);
            f32x16 pv;
            #pragma unroll
            for (int t = 0; t < 16; ++t) pv[t] = __expf(fabsf(S[t]));  // s in [0,1]
            short8 pb0, pb1;
            pack_swap16(pv, pb0, pb1);                     // B-frags: col i, k = j
            short8 va0 = ld8(&vxT[ncl][jt * 32 + 8 * hi]); // A-frags: row d, k = j
            short8 va1 = ld8(&vxT[ncl][jt * 32 + 16 + 8 * hi]);
            Oacc = __builtin_amdgcn_mfma_f32_32x32x16_bf16(va0, pb0, Oacc, 0, 0, 0);
            Oacc = __builtin_amdgcn_mfma_f32_32x32x16_bf16(va1, pb1, Oacc, 0, 0, 0);
        }
    }

    // ---------------- P3: residual + LN2, in-register (lane pairs) ------------
    // Oacc[8] = row 16 (hi=0) / 20 (hi=1); rows 16..31 all = l (clamped ones-row)
    const float rl = 1.0f / Oacc[8];
    float o1[8];
    o1[0] = xra.x + Oacc[0] * rl;  o1[1] = xra.y + Oacc[1] * rl;
    o1[2] = xra.z + Oacc[2] * rl;  o1[3] = xra.w + Oacc[3] * rl;
    o1[4] = xrb.x + Oacc[4] * rl;  o1[5] = xrb.y + Oacc[5] * rl;
    o1[6] = xrb.z + Oacc[6] * rl;  o1[7] = xrb.w + Oacc[7] * rl;

    float s8 = 0.0f;
    #pragma unroll
    for (int t = 0; t < 8; ++t) s8 += o1[t];
    float mu2 = (s8 + __shfl_xor(s8, 32, 64)) * (1.0f / DD);
    float v8 = 0.0f;
    #pragma unroll
    for (int t = 0; t < 8; ++t) { float dv = o1[t] - mu2; v8 += dv * dv; }
    float var2 = (v8 + __shfl_xor(v8, 32, 64)) * (1.0f / DD);
    float rs2 = 1.0f / sqrtf(var2 + 1e-5f);

    const float4 g0v = *(const float4*)&ln2g_lds[4 * hi];
    const float4 g1v = *(const float4*)&ln2g_lds[8 + 4 * hi];
    const float4 bb0 = *(const float4*)&ln2b_lds[4 * hi];
    const float4 bb1 = *(const float4*)&ln2b_lds[8 + 4 * hi];
    float h[8];
    h[0] = (o1[0]-mu2)*rs2*g0v.x + bb0.x;  h[1] = (o1[1]-mu2)*rs2*g0v.y + bb0.y;
    h[2] = (o1[2]-mu2)*rs2*g0v.z + bb0.z;  h[3] = (o1[3]-mu2)*rs2*g0v.w + bb0.w;
    h[4] = (o1[4]-mu2)*rs2*g1v.x + bb1.x;  h[5] = (o1[5]-mu2)*rs2*g1v.y + bb1.y;
    h[6] = (o1[6]-mu2)*rs2*g1v.z + bb1.z;  h[7] = (o1[7]-mu2)*rs2*g1v.w + bb1.w;

    short8 hB;   // B-frag (col = token, k = d)
    {
        u32 w0, w1u, w2u, w3;
        asm("v_cvt_pk_bf16_f32 %0, %1, %2" : "=v"(w0)  : "v"(h[0]), "v"(h[1]));
        asm("v_cvt_pk_bf16_f32 %0, %1, %2" : "=v"(w1u) : "v"(h[2]), "v"(h[3]));
        asm("v_cvt_pk_bf16_f32 %0, %1, %2" : "=v"(w2u) : "v"(h[4]), "v"(h[5]));
        asm("v_cvt_pk_bf16_f32 %0, %1, %2" : "=v"(w3)  : "v"(h[6]), "v"(h[7]));
        asm("s_nop 1\n\tv_permlane32_swap_b32 %0, %1" : "+v"(w0),  "+v"(w2u));
        asm("s_nop 1\n\tv_permlane32_swap_b32 %0, %1" : "+v"(w1u), "+v"(w3));
        struct { u32 x, y, z, w; } hw{w0, w1u, w2u, w3};
        hB = __builtin_bit_cast(short8, hw);
    }

    // ---------------- P4: MLP via MFMA, all in lane=token orientation ---------
    const int dcl = (l31 < 15) ? l31 : 15;   // w2 A-frag row clamp
    f32x16 O2 = zc;
    {
        const float4 c0 = *(const float4*)&b2_lds[4 * hi];
        const float4 c1 = *(const float4*)&b2_lds[8 + 4 * hi];
        O2[0] = c0.x; O2[1] = c0.y; O2[2] = c0.z; O2[3] = c0.w;
        O2[4] = c1.x; O2[5] = c1.y; O2[6] = c1.z; O2[7] = c1.w;
    }
    #pragma unroll
    for (int kblk = 0; kblk < 2; ++kblk) {
        f32x16 Hc;
        {
            const float* bp = &b1_lds[32 * kblk];
            const float4 c0 = *(const float4*)(bp + 4 * hi);
            const float4 c1 = *(const float4*)(bp + 8 + 4 * hi);
            const float4 c2 = *(const float4*)(bp + 16 + 4 * hi);
            const float4 c3 = *(const float4*)(bp + 24 + 4 * hi);
            Hc[0]=c0.x; Hc[1]=c0.y; Hc[2]=c0.z; Hc[3]=c0.w;
            Hc[4]=c1.x; Hc[5]=c1.y; Hc[6]=c1.z; Hc[7]=c1.w;
            Hc[8]=c2.x; Hc[9]=c2.y; Hc[10]=c2.z; Hc[11]=c2.w;
            Hc[12]=c3.x; Hc[13]=c3.y; Hc[14]=c3.z; Hc[15]=c3.w;
        }
        short8 w1f = ld8(&w1tb[32 * kblk + l31][8 * hi]);
        f32x16 H = __builtin_amdgcn_mfma_f32_32x32x16_bf16(w1f, hB, Hc, 0, 0, 0);
        f32x16 gv;
        #pragma unroll
        for (int t = 0; t < 16; ++t) gv[t] = gelu_erf(H[t]);
        short8 gb0, gb1;
        pack_swap16(gv, gb0, gb1);
        short8 w2f0 = ld8(&w2tb[dcl][32 * kblk + 8 * hi]);
        short8 w2f1 = ld8(&w2tb[dcl][32 * kblk + 16 + 8 * hi]);
        O2 = __builtin_amdgcn_mfma_f32_32x32x16_bf16(w2f0, gb0, O2, 0, 0, 0);
        O2 = __builtin_amdgcn_mfma_f32_32x32x16_bf16(w2f1, gb1, O2, 0, 0, 0);
    }

    // ---------------- P5: out = o1 + O2 (+b2 already in O2), direct store -----
    {
        float* orow = out + ((size_t)b * NTOK + 32 * w + l31) * DD;
        float4 oa, ob;
        oa.x = o1[0] + O2[0]; oa.y = o1[1] + O2[1];
        oa.z = o1[2] + O2[2]; oa.w = o1[3] + O2[3];
        ob.x = o1[4] + O2[4]; ob.y = o1[5] + O2[5];
        ob.z = o1[6] + O2[6]; ob.w = o1[7] + O2[7];
        *(float4*)(orow + 4 * hi) = oa;
        *(float4*)(orow + 8 + 4 * hi) = ob;
    }
}

extern "C" void kernel_launch(void* const* d_in, const int* in_sizes, int n_in,
                              void* d_out, int out_size, void* d_ws, size_t ws_size,
                              hipStream_t stream) {
    const float* x     = (const float*)d_in[0];
    const float* ln1_g = (const float*)d_in[1];
    const float* ln1_b = (const float*)d_in[2];
    const float* ang   = (const float*)d_in[3];
    const float* ln2_g = (const float*)d_in[4];
    const float* ln2_b = (const float*)d_in[5];
    const float* w1    = (const float*)d_in[6];
    const float* b1    = (const float*)d_in[7];
    const float* w2    = (const float*)d_in[8];
    const float* b2    = (const float*)d_in[9];
    float* out = (float*)d_out;

    const int B = in_sizes[0] / (NTOK * DD);
    hipLaunchKernelGGL(qab_kernel, dim3(B), dim3(BDIM), 0, stream,
                       x, ln1_g, ln1_b, ang, ln2_g, ln2_b, w1, b1, w2, b2, out);
}